// Round 11
// baseline (502.036 us; speedup 1.0000x reference)
//
#include <hip/hip_runtime.h>
#include <cstdint>
#include <cstddef>

#define DI __device__ __forceinline__

typedef unsigned short u16;

// ---------------- problem constants ----------------
constexpr int B_ = 2, T_ = 1024, C_ = 2048, H_ = 32, N_ = 64;
constexpr int BT = B_ * T_;            // 2048 rows
constexpr float GN_EPS_C = 64e-5f;     // N * 1e-5
constexpr int LCH = 64;                // scan chunk length
constexpr int NC = T_ / LCH;           // 16 chunks
constexpr int UNITS = B_ * H_ * NC;    // 1024 (b,h,chunk) units

// ---------------- small helpers ----------------
DI float bf2f(u16 h) {
    union { unsigned u; float f; } x; x.u = ((unsigned)h) << 16; return x.f;
}
DI u16 f2bf(float f) {
    union { float f; unsigned u; } x; x.f = f;
    unsigned r = (x.u + 0x7fffu + ((x.u >> 16) & 1u)) >> 16;
    return (u16)r;
}
DI float sigmoidf_(float x) { return 1.f / (1.f + __expf(-x)); }
DI float tanhf_(float x) { float e = __expf(2.f * x); return 1.f - 2.f / (e + 1.f); }

typedef __attribute__((ext_vector_type(8))) __bf16 bf16x8;
typedef __attribute__((ext_vector_type(4))) float f32x4;

DI void gload16(const void* g, void* l) {
    __builtin_amdgcn_global_load_lds(
        (const __attribute__((address_space(1))) void*)g,
        (__attribute__((address_space(3))) void*)l,
        16, 0, 0);
}

// ---------------- epilogue ids ----------------
enum { EP_BF16 = 0, EP_F32 = 1, EP_TANH = 2, EP_SIG = 3, EP_LDECAY = 4, EP_ASIG = 5, EP_VMIX = 6 };

// ---------------- deep-K 128x128 bf16 MFMA GEMM core, BK=128 (r4-proven) ----------------
// 4 K-slices (64KB LDS) per barrier pair: 16 drains/block at K=2048 (was 32 at BK=64).
// Round-4 measured this core at 636 TF on the rkv shapes vs 558 TF for BK=64.
// Each slice keeps the verified [128][32] sub-tile layout (offset s*4096).
DI void gemm_core(const u16* __restrict__ A, int lda,
                  const u16* __restrict__ Bt, int ldb,
                  void* __restrict__ Out, int ldc,
                  int Nreal, int K, int m0, int n0, int epi,
                  const float* __restrict__ aux0, const float* __restrict__ aux1) {
    __shared__ u16 lA[4 * 4096];   // 4 slices x [128][32]
    __shared__ u16 lB[4 * 4096];
    const int tid = threadIdx.x;
    const int lane = tid & 63;
    const int wv = tid >> 6;
    const int wr = wv >> 1, wc = wv & 1;
    const int r0 = tid >> 2;
    const int cc0 = (tid & 3) * 8;

    f32x4 acc[4][4];
#pragma unroll
    for (int i = 0; i < 4; i++)
#pragma unroll
        for (int j = 0; j < 4; j++) acc[i][j] = (f32x4){0.f, 0.f, 0.f, 0.f};

    const u16* Abase = A + (size_t)(m0 + r0) * lda + cc0;
    const u16* Bbase = Bt + (size_t)(n0 + r0) * ldb + cc0;
    const int stoff = r0 * 32 + cc0;

    for (int k0 = 0; k0 < K; k0 += 128) {
        const int ns = min(4, (K - k0) >> 5);   // K always a multiple of 32 here
        __syncthreads();
        for (int s = 0; s < ns; s++) {
            const int ko = k0 + s * 32;
            u16* la = lA + s * 4096;
            u16* lb = lB + s * 4096;
            gload16(Abase + ko, la + stoff);
            gload16(Abase + (size_t)64 * lda + ko, la + 2048 + stoff);
            gload16(Bbase + ko, lb + stoff);
            gload16(Bbase + (size_t)64 * ldb + ko, lb + 2048 + stoff);
        }
        __syncthreads();
        for (int s = 0; s < ns; s++) {
            const u16* la = lA + s * 4096;
            const u16* lb = lB + s * 4096;
            bf16x8 af[4], bfr[4];
#pragma unroll
            for (int i = 0; i < 4; i++) {
                af[i]  = *(const bf16x8*)&la[(wr * 64 + i * 16 + (lane & 15)) * 32 + (lane >> 4) * 8];
                bfr[i] = *(const bf16x8*)&lb[(wc * 64 + i * 16 + (lane & 15)) * 32 + (lane >> 4) * 8];
            }
#pragma unroll
            for (int mi = 0; mi < 4; mi++)
#pragma unroll
                for (int ni = 0; ni < 4; ni++)
                    acc[mi][ni] = __builtin_amdgcn_mfma_f32_16x16x32_bf16(af[mi], bfr[ni], acc[mi][ni], 0, 0, 0);
        }
    }

#pragma unroll
    for (int mi = 0; mi < 4; mi++) {
#pragma unroll
        for (int ni = 0; ni < 4; ni++) {
            int n = n0 + wc * 64 + ni * 16 + (lane & 15);
            if (n >= Nreal) continue;
#pragma unroll
            for (int rg = 0; rg < 4; rg++) {
                int m = m0 + wr * 64 + mi * 16 + (lane >> 4) * 4 + rg;
                size_t ix = (size_t)m * ldc + n;
                float f = acc[mi][ni][rg];
                switch (epi) {
                    case EP_BF16: ((u16*)Out)[ix] = f2bf(f); break;
                    case EP_F32:  ((float*)Out)[ix] = f; break;
                    case EP_TANH: ((u16*)Out)[ix] = f2bf(tanhf_(f)); break;
                    case EP_SIG:  ((u16*)Out)[ix] = f2bf(sigmoidf_(f)); break;
                    case EP_LDECAY: {
                        // store LOG of decay: lw = -exp(-0.5 - softplus(-(w0+f)))
                        float z = -(aux0[n] + f);
                        float sp = (z > 15.f) ? z : __logf(1.f + __expf(z));
                        ((float*)Out)[ix] = -__expf(-0.5f - sp);
                    } break;
                    case EP_ASIG: ((u16*)Out)[ix] = f2bf(sigmoidf_(aux0[n] + f)); break;
                    case EP_VMIX: {
                        float vs = sigmoidf_(aux0[n] + f);
                        float old = bf2f(((u16*)Out)[ix]);
                        float vf = aux1[ix];
                        ((u16*)Out)[ix] = f2bf(old + (vf - old) * vs);
                    } break;
                }
            }
        }
    }
}

// ---- merged r/k/v projections + LoRA up-projections (independent work, one dispatch) ----
__global__ __launch_bounds__(256, 1) void k_rkvup(const u16* xmix,
    const u16* WrT, const u16* WkT, const u16* WvT,
    const u16* w1T, const u16* a1T, const u16* v1T, const u16* g1T,
    u16* rb, u16* kb, u16* vb, float* hp) {
    int z = blockIdx.z;
    if (z < 3) {
        const int sel[3] = {0, 2, 3};  // xr, xk, xv
        const u16* A = xmix + (size_t)sel[z] * BT * C_;
        const u16* Bt = (z == 0) ? WrT : (z == 1) ? WkT : WvT;
        u16* Out = (z == 0) ? rb : (z == 1) ? kb : vb;
        gemm_core(A, C_, Bt, C_, Out, C_, C_, C_, blockIdx.y * 128, blockIdx.x * 128,
                  EP_BF16, nullptr, nullptr);
    } else {
        int zz = z - 3;
        int flat = blockIdx.y * 16 + blockIdx.x;   // 0..255
        const int nact[4] = {64, 64, 64, 128};
        if (flat >= nact[zz]) return;
        int ksp, mb, n0;
        if (zz < 3) { ksp = flat >> 4; mb = flat & 15; n0 = 0; }
        else        { ksp = flat >> 5; int rem = flat & 31; mb = rem >> 1; n0 = (rem & 1) * 128; }
        const int sel[4]   = {1, 4, 3, 5};        // xw, xa, xv, xg
        const int nreal[4] = {96, 96, 64, 256};
        const int coff[4]  = {0, 96, 192, 256};
        const u16* Bt = (zz == 0) ? w1T : (zz == 1) ? a1T : (zz == 2) ? v1T : g1T;
        gemm_core(xmix + (size_t)sel[zz] * BT * C_ + ksp * 512, C_, Bt + ksp * 512, C_,
                  hp + (size_t)ksp * BT * 512 + coff[zz], 512, nreal[zz], 512,
                  mb * 128, n0, EP_F32, nullptr, nullptr);
    }
}

// reduce the 4 split-K partials + apply per-column activation -> hbuf (bf16)
__global__ void k_upred(const float* __restrict__ hp, u16* __restrict__ hbuf) {
    int idx = (blockIdx.x * 256 + threadIdx.x) * 4;   // over 2048*512 elements
    int col = idx & 511;
    const size_t HP = (size_t)BT * 512;
    float4 s = *(const float4*)(hp + idx);
#pragma unroll
    for (int p = 1; p < 4; p++) {
        float4 t = *(const float4*)(hp + p * HP + idx);
        s.x += t.x; s.y += t.y; s.z += t.z; s.w += t.w;
    }
    ushort4 o;
    if (col < 96) {
        o.x = f2bf(tanhf_(s.x)); o.y = f2bf(tanhf_(s.y));
        o.z = f2bf(tanhf_(s.z)); o.w = f2bf(tanhf_(s.w));
    } else if (col < 256) {
        o.x = f2bf(s.x); o.y = f2bf(s.y); o.z = f2bf(s.z); o.w = f2bf(s.w);
    } else {
        o.x = f2bf(sigmoidf_(s.x)); o.y = f2bf(sigmoidf_(s.y));
        o.z = f2bf(sigmoidf_(s.z)); o.w = f2bf(sigmoidf_(s.w));
    }
    *(ushort4*)(hbuf + idx) = o;
}

// ---- fused LoRA down-projections (z 0..3) ----
__global__ __launch_bounds__(256, 1) void k_down4(const u16* hbuf, const u16* w2T, const u16* a2T,
                                                  const u16* v2T, const u16* g2T,
                                                  float* lwdec, u16* asig, u16* vbuf, u16* gbuf,
                                                  const float* w0, const float* a0, const float* v0,
                                                  const float* vfirst) {
    int z = blockIdx.z;
    const int Ks[4]   = {96, 96, 64, 256};
    const int coff[4] = {0, 96, 192, 256};
    const int epi[4]  = {EP_LDECAY, EP_ASIG, EP_VMIX, EP_BF16};
    const u16* Bt = (z == 0) ? w2T : (z == 1) ? a2T : (z == 2) ? v2T : g2T;
    void* Out = (z == 0) ? (void*)lwdec : (z == 1) ? (void*)asig : (z == 2) ? (void*)vbuf : (void*)gbuf;
    const float* aux0 = (z == 0) ? w0 : (z == 1) ? a0 : (z == 2) ? v0 : nullptr;
    const float* aux1 = (z == 2) ? vfirst : nullptr;
    gemm_core(hbuf + coff[z], 512, Bt, Ks[z], Out, 2048, 2048, Ks[z],
              blockIdx.y * 128, blockIdx.x * 128, epi[z], aux0, aux1);
}

// ---- output projection: split-K=2 (512 blocks, K=1024 chains) + deterministic reduce ----
__global__ __launch_bounds__(256, 1) void k_oproj(const u16* yg, const u16* WoT, float* opart) {
    int ksp = blockIdx.z;
    gemm_core(yg + ksp * 1024, 2048, WoT + ksp * 1024, 2048,
              opart + (size_t)ksp * BT * C_, 2048, 2048, 1024,
              blockIdx.y * 128, blockIdx.x * 128, EP_F32, nullptr, nullptr);
}

__global__ void k_ored(const float* __restrict__ p, float* __restrict__ out) {
    int idx = (blockIdx.x * 256 + threadIdx.x) * 4;
    const size_t S = (size_t)BT * C_;
    float4 a = *(const float4*)(p + idx);
    float4 b = *(const float4*)(p + S + idx);
    float4 o = {a.x + b.x, a.y + b.y, a.z + b.z, a.w + b.w};
    *(float4*)(out + idx) = o;
}

// ---------------- merged preprocessing: transposes + token-shift mix ----------------
struct TDesc { const float* in; u16* out; int K; int N; };
struct PreArgs {
    TDesc big[4];
    TDesc sm[8];
    const float* x;
    const float* cs[6];
    u16* xmix;
};

DI void transpose_tile(TDesc dd, int k0, int n0, int tidx) {
    __shared__ float tile[32][33];
    int tx = tidx & 31, ty = tidx >> 5;
#pragma unroll
    for (int i = 0; i < 32; i += 8)
        tile[ty + i][tx] = dd.in[(size_t)(k0 + ty + i) * dd.N + (n0 + tx)];
    __syncthreads();
#pragma unroll
    for (int i = 0; i < 32; i += 8)
        dd.out[(size_t)(n0 + ty + i) * dd.K + (k0 + tx)] = f2bf(tile[tx][ty + i]);
}

// grid (64,64,6): z<4 big 2048^2 transposes; z==4 packed small transposes; z==5 mix
__global__ void k_pre(PreArgs a) {
    int z = blockIdx.z;
    if (z < 4) {
        transpose_tile(a.big[z], blockIdx.x * 32, blockIdx.y * 32, threadIdx.x);
        return;
    }
    if (z == 4) {
        int flat = blockIdx.y * 64 + blockIdx.x;
        const int cnt[8] = {192, 192, 128, 512, 192, 192, 128, 512};  // (K/32)*(N/32) per mat
        int d = 0, loc = flat;
        while (d < 8 && loc >= cnt[d]) { loc -= cnt[d]; d++; }
        if (d >= 8) return;
        TDesc dd = a.sm[d];
        int nn = dd.N >> 5;
        transpose_tile(dd, (loc / nn) * 32, (loc % nn) * 32, threadIdx.x);
        return;
    }
    // z == 5: token-shift mix (x4 vectorized)
    int idx = (blockIdx.y * 64 + blockIdx.x) * 256 + threadIdx.x;
    int base = idx * 4;
    int c4 = base & (C_ - 1);
    int bt = base >> 11;
    int t = bt & (T_ - 1);
    float4 xv = *(const float4*)(a.x + base);
    float4 xp = (t == 0) ? (float4){0.f, 0.f, 0.f, 0.f} : *(const float4*)(a.x + base - C_);
    float4 dx = {xp.x - xv.x, xp.y - xv.y, xp.z - xv.z, xp.w - xv.w};
    const size_t S = (size_t)BT * C_;
#pragma unroll
    for (int j = 0; j < 6; j++) {
        float4 cc = *(const float4*)(a.cs[j] + c4);
        ushort4 o;
        o.x = f2bf(xv.x + dx.x * cc.x);
        o.y = f2bf(xv.y + dx.y * cc.y);
        o.z = f2bf(xv.z + dx.z * cc.z);
        o.w = f2bf(xv.w + dx.w * cc.w);
        *(ushort4*)(a.xmix + j * S + base) = o;
    }
}

// ================= chunked WKV7 scan =================
DI bf16x8 frag64(const u16* p, int row, int ks, int lane) {
    return *(const bf16x8*)&p[(row + (lane & 15)) * 64 + ks * 32 + (lane >> 4) * 8];
}

DI void g64(const u16* lA, const u16* lB, f32x4 acc[2][2], int m0, int n0, int lane) {
#pragma unroll
    for (int ks = 0; ks < 2; ks++) {
        bf16x8 a0 = frag64(lA, m0, ks, lane);
        bf16x8 a1 = frag64(lA, m0 + 16, ks, lane);
        bf16x8 b0 = frag64(lB, n0, ks, lane);
        bf16x8 b1 = frag64(lB, n0 + 16, ks, lane);
        acc[0][0] = __builtin_amdgcn_mfma_f32_16x16x32_bf16(a0, b0, acc[0][0], 0, 0, 0);
        acc[0][1] = __builtin_amdgcn_mfma_f32_16x16x32_bf16(a0, b1, acc[0][1], 0, 0, 0);
        acc[1][0] = __builtin_amdgcn_mfma_f32_16x16x32_bf16(a1, b0, acc[1][0], 0, 0, 0);
        acc[1][1] = __builtin_amdgcn_mfma_f32_16x16x32_bf16(a1, b1, acc[1][1], 0, 0, 0);
    }
}

DI void stage8k(const u16* g, u16* l, int tid) {   // 4096 u16 = 8KB
    gload16(g + tid * 8, l + tid * 8);
    gload16(g + 2048 + tid * 8, l + 2048 + tid * 8);
}

// ---- FUSED A1+A2: block-scan decay cumsum + head prep directly into LDS, then
//      U -> inversion -> PB/PK/Qt/VQ -> G1T/VQM. Ahat/Bhat/Khat never touch HBM.
//      NOTE: sV is built [v][t] (transposed) — P4 consumes it exactly like the old
//      k_chunkops consumed the staged GLOBAL Vt (which k_prepA wrote transposed).
__global__ __launch_bounds__(256, 1) void k_prepchunk(
    const float* __restrict__ lwdec, const u16* __restrict__ asig,
    u16* __restrict__ kb, const u16* __restrict__ rb, const u16* __restrict__ vb,
    const float* __restrict__ k_k, const float* __restrict__ k_a,
    u16* __restrict__ Rhat, u16* __restrict__ Vt, u16* __restrict__ BhatT,
    u16* __restrict__ KhatT, float* __restrict__ cumLg,
    u16* __restrict__ PB, u16* __restrict__ PK, u16* __restrict__ G1T, u16* __restrict__ VQM) {
    __shared__ u16 sA[4096], sB[4096], sK[4096], sR[4096], sV[4096], sQt[4096], sAT[4096];
    __shared__ float Uf[64 * 65];
    __shared__ float wsum[4][64];
    int tid = threadIdx.x, wv = tid >> 6, lane = tid & 63;
    int unit = blockIdx.x;
    int c = unit & 15, bh = unit >> 4, h = bh & 31, b = bh >> 5;
    size_t ub = (size_t)unit * 4096;
    int m0 = (wv >> 1) * 32, n0 = (wv & 1) * 32;
    u16* sMt = sB;   // alias: sB dead after P2
    u16* sVQ = sR;   // alias: sR dead after P2

    // ---- P0a: wave-local decay sums (wave wv owns t in [wv*16, wv*16+16)) ----
    int cg = h * 64 + lane;
    float kkc = k_k[cg], kac = k_a[cg];
    int t0 = wv * 16;
    size_t gbase = (((size_t)b * 1024 + c * 64 + t0) * 32 + h) * 64 + lane;  // +2048 per t
    float ls = 0.f;
#pragma unroll
    for (int i = 0; i < 16; i++) ls += lwdec[gbase + (size_t)i * 2048];
    wsum[wv][lane] = ls;
    __syncthreads();
    float cs = 0.f;
    for (int w = 0; w < wv; w++) cs += wsum[w][lane];

    // ---- P0b: head prep (kk-norm, k-mod) + hat vectors into LDS ----
#pragma unroll 4
    for (int i = 0; i < 16; i++) {
        int t = t0 + i;
        size_t gi = gbase + (size_t)i * 2048;
        float lw = lwdec[gi];
        float kraw = bf2f(kb[gi]);
        float ic = bf2f(asig[gi]);
        float r = bf2f(rb[gi]), v = bf2f(vb[gi]);
        float kkv = kraw * kkc;
        float ss = kkv * kkv;
#pragma unroll
        for (int m = 32; m >= 1; m >>= 1) ss += __shfl_xor(ss, m, 64);
        float kk = kkv * (1.f / fmaxf(sqrtf(ss), 1e-12f));
        float kmod = kraw * fmaf(ic - 1.f, kac, 1.f);
        kb[gi] = f2bf(kmod);
        float cum_prev = __expf(cs);   // cs = sum of lw over t' < t
        cs += lw;
        float cum = __expf(cs);
        float inv = __expf(-cs);
        sA[t * 64 + lane] = f2bf(-kk * cum_prev);
        u16 rh_ = f2bf(r * cum);
        sR[t * 64 + lane] = rh_;
        Rhat[ub + t * 64 + lane] = rh_;
        sB[t * 64 + lane] = f2bf(kk * ic * inv);
        sK[t * 64 + lane] = f2bf(kmod * inv);
        sV[lane * 64 + t] = f2bf(v);   // [v][t] — matches old staged-global Vt layout for P4
    }
    if (wv == 3) cumLg[(size_t)unit * 64 + lane] = __expf(cs);
    __syncthreads();

    // ---- global copies for scan/youtgn (waves 0/1/2; wave3 goes straight to P1) ----
    if (wv < 3) {
        if (wv == 2) {
            // sV already [v][t]; straight vector copy to global Vt
            uint4* s = (uint4*)(sV + lane * 64);
            uint4* p = (uint4*)(Vt + ub + lane * 64);
#pragma unroll
            for (int i = 0; i < 8; i++) p[i] = s[i];
        } else {
            const u16* src = (wv == 0) ? sB : sK;
            u16* dst = (wv == 0) ? BhatT : KhatT;
            union U64x { u16 hh[64]; uint4 q[8]; } tm;
#pragma unroll
            for (int t = 0; t < 64; t++) tm.hh[t] = src[t * 64 + lane];
            uint4* p = (uint4*)(dst + ub + lane * 64);
#pragma unroll
            for (int i = 0; i < 8; i++) p[i] = tm.q[i];
        }
    }

    // P1: U[s][t] (strict upper) + AhatT
    {
        f32x4 acc[2][2] = {};
        g64(sB, sA, acc, m0, n0, lane);
#pragma unroll
        for (int mi = 0; mi < 2; mi++)
#pragma unroll
            for (int ni = 0; ni < 2; ni++)
#pragma unroll
                for (int rg = 0; rg < 4; rg++) {
                    int m = m0 + mi * 16 + (lane >> 4) * 4 + rg;   // s
                    int n = n0 + ni * 16 + (lane & 15);            // t
                    Uf[m * 65 + n] = (m < n) ? acc[mi][ni][rg] : 0.f;
                }
#pragma unroll
        for (int i = 0; i < 16; i++) {
            int idx = tid * 16 + i;
            int k = idx >> 6, s = idx & 63;
            sAT[idx] = sA[s * 64 + k];
        }
    }
    __syncthreads();

    // P2: PB, PK (global) + Qt (LDS)
    {
        f32x4 a1[2][2] = {}, a2[2][2] = {}, a3[2][2] = {};
        g64(sR, sB, a1, m0, n0, lane);
        g64(sR, sK, a2, m0, n0, lane);
        g64(sA, sK, a3, m0, n0, lane);
#pragma unroll
        for (int mi = 0; mi < 2; mi++)
#pragma unroll
            for (int ni = 0; ni < 2; ni++)
#pragma unroll
                for (int rg = 0; rg < 4; rg++) {
                    int m = m0 + mi * 16 + (lane >> 4) * 4 + rg;
                    int n = n0 + ni * 16 + (lane & 15);
                    PB[ub + m * 64 + n] = f2bf((n <= m) ? a1[mi][ni][rg] : 0.f);
                    PK[ub + m * 64 + n] = f2bf((n <= m) ? a2[mi][ni][rg] : 0.f);
                    sQt[m * 64 + n] = f2bf((n < m) ? a3[mi][ni][rg] : 0.f);
                }
    }
    __syncthreads();

    // P3: blocked inversion of (I-U), in place in Uf. Blocks 16x16.
    if (lane < 16) {
        int s0 = wv * 16, t = lane;
        Uf[(s0 + 15) * 65 + (s0 + t)] = (t == 15) ? 1.f : 0.f;
        for (int s = 14; s >= 0; s--) {
            float acc = (t == s) ? 1.f : 0.f;
            for (int u = s + 1; u < 16; u++)
                acc += Uf[(s0 + s) * 65 + (s0 + u)] * Uf[(s0 + u) * 65 + (s0 + t)];
            Uf[(s0 + s) * 65 + (s0 + t)] = acc;
        }
    }
    __syncthreads();
    for (int j = 1; j <= 3; j++) {
        float Xn[4];
        int t = lane & 15, q = lane >> 4;
        bool act = (wv < j);
        if (act) {
            int i = wv;
            float Wreg[4];
#pragma unroll
            for (int ri = 0; ri < 4; ri++) {
                int r = q * 4 + ri;
                float w = 0.f;
                for (int p = i; p < j; p++)
#pragma unroll
                    for (int u = 0; u < 16; u++)
                        w += Uf[(i * 16 + r) * 65 + p * 16 + u] * Uf[(p * 16 + u) * 65 + j * 16 + t];
                Wreg[ri] = w;
            }
#pragma unroll
            for (int ri = 0; ri < 4; ri++) {
                float acc = 0.f;
#pragma unroll
                for (int u = 0; u < 16; u++)
                    acc += __shfl(Wreg[ri], (lane & 48) + u, 64) * Uf[(j * 16 + u) * 65 + (j * 16 + t)];
                Xn[ri] = acc;
            }
        }
        __syncthreads();
        if (act) {
#pragma unroll
            for (int ri = 0; ri < 4; ri++)
                Uf[(wv * 16 + q * 4 + ri) * 65 + j * 16 + t] = Xn[ri];
        }
        __syncthreads();
    }
    // sMt[t][s] = X[s][t] (bf16)
#pragma unroll
    for (int i = 0; i < 16; i++) {
        int idx = tid * 16 + i;
        int t = idx >> 6, s = idx & 63;
        sMt[idx] = f2bf((s <= t) ? Uf[s * 65 + t] : 0.f);
    }
    __syncthreads();

    // P4: VQ = Vt x Qt^T -> sVQ  (sV is [v][t], same as old staged-global layout)
    {
        f32x4 acc[2][2] = {};
        g64(sV, sQt, acc, m0, n0, lane);
#pragma unroll
        for (int mi = 0; mi < 2; mi++)
#pragma unroll
            for (int ni = 0; ni < 2; ni++)
#pragma unroll
                for (int rg = 0; rg < 4; rg++) {
                    int m = m0 + mi * 16 + (lane >> 4) * 4 + rg;
                    int n = n0 + ni * 16 + (lane & 15);
                    sVQ[m * 64 + n] = f2bf(acc[mi][ni][rg]);
                }
    }
    __syncthreads();

    // P5: VQM = VQ x X ; G1T[t][k] = sum_s X[s][t] Ahat[s][k]
    {
        f32x4 a1[2][2] = {}, a2[2][2] = {};
        g64(sVQ, sMt, a1, m0, n0, lane);
        g64(sMt, sAT, a2, m0, n0, lane);
#pragma unroll
        for (int mi = 0; mi < 2; mi++)
#pragma unroll
            for (int ni = 0; ni < 2; ni++)
#pragma unroll
                for (int rg = 0; rg < 4; rg++) {
                    int m = m0 + mi * 16 + (lane >> 4) * 4 + rg;
                    int n = n0 + ni * 16 + (lane & 15);
                    VQM[ub + m * 64 + n] = f2bf(a1[mi][ni][rg]);
                    G1T[ub + m * 64 + n] = f2bf(a2[mi][ni][rg]);
                }
    }
}

// ---- B: sequential chunk recurrence, SPLIT over state rows v (fully row-parallel).
//      Block (bh, half) owns rows v in [half*32, half*32+32). 128 blocks (2x CUs vs 64).
//      Shared operands G1T/BhatT/KhatT staged in full; VQM/Vt/S halved.
//      Waves 0,1 compute the 32x64 tile (n0 = wv*32); waves 2,3 only help staging.
//      All __syncthreads() executed uniformly by all 256 threads.
__global__ __launch_bounds__(256, 1) void k_scanBl(
    const u16* __restrict__ G1T, const u16* __restrict__ VQM, const u16* __restrict__ BhatT,
    const u16* __restrict__ KhatT, const u16* __restrict__ Vt, const float* __restrict__ cumLg,
    u16* __restrict__ SA, u16* __restrict__ Sin) {
    __shared__ u16 bG1[2][4096], bBh[2][4096], bKh[2][4096];
    __shared__ u16 bVQ[2][2048], bVt[2][2048];
    __shared__ u16 sSA[2048], sS[2048];
    __shared__ float sSf[2048];
    __shared__ float sCumL[2][64];

    int tid = threadIdx.x, wv = tid >> 6, lane = tid & 63;
    int bh = blockIdx.x >> 1;
    int half = blockIdx.x & 1;
    int hoff = half * 2048;            // element offset of our 32-row half in [64][64] bufs
    int n0 = (wv & 1) * 32;            // waves 0,1: n-halves; waves 2,3 idle in MFMA

    for (int i = tid; i < 2048; i += 256) { sSf[i] = 0.f; sS[i] = 0; }
    {   // Sin chunk 0 = zeros (our half)
        uint4 z = {0, 0, 0, 0};
        uint4* p = (uint4*)(Sin + (size_t)bh * NC * 4096 + hoff);
        for (int i = tid; i < 256; i += 256) p[i] = z;
    }

    auto stage = [&](int c, int buf) {
        size_t ub = ((size_t)bh * NC + c) * 4096;
        stage8k(G1T + ub, bG1[buf], tid);
        stage8k(BhatT + ub, bBh[buf], tid);
        stage8k(KhatT + ub, bKh[buf], tid);
        gload16(VQM + ub + hoff + tid * 8, bVQ[buf] + tid * 8);   // 2048 u16 = 256x16B
        gload16(Vt + ub + hoff + tid * 8, bVt[buf] + tid * 8);
        if (tid < 16) gload16(cumLg + ((size_t)bh * NC + c) * 64 + tid * 4, &sCumL[buf][tid * 4]);
    };

    stage(0, 0);
    for (int c = 0; c < NC; c++) {
        int cur = c & 1;
        __syncthreads();                  // B1: staged data + prev S' visible
        if (c + 1 < NC) stage(c + 1, 1 - cur);
        size_t ub = ((size_t)bh * NC + c) * 4096;

        // gSA: SA = S x G1T-form + VQM   (rows v local 0..32)
        if (wv < 2) {
            f32x4 acc[2][2];
#pragma unroll
            for (int mi = 0; mi < 2; mi++)
#pragma unroll
                for (int ni = 0; ni < 2; ni++)
#pragma unroll
                    for (int rg = 0; rg < 4; rg++) {
                        int m = mi * 16 + (lane >> 4) * 4 + rg;
                        int n = n0 + ni * 16 + (lane & 15);
                        acc[mi][ni][rg] = bf2f(bVQ[cur][m * 64 + n]);
                    }
            g64(sS, bG1[cur], acc, 0, n0, lane);
#pragma unroll
            for (int mi = 0; mi < 2; mi++)
#pragma unroll
                for (int ni = 0; ni < 2; ni++)
#pragma unroll
                    for (int rg = 0; rg < 4; rg++) {
                        int m = mi * 16 + (lane >> 4) * 4 + rg;
                        int n = n0 + ni * 16 + (lane & 15);
                        u16 h = f2bf(acc[mi][ni][rg]);
                        sSA[m * 64 + n] = h;
                        SA[ub + (size_t)(m + half * 32) * 64 + n] = h;
                    }
        }
        __syncthreads();                  // B2 (also drains prefetch)

        // gS': S' = (S + SA.bhat + Vt.khat) * cumL[k]
        if (wv < 2) {
            f32x4 acc[2][2] = {};
            g64(sSA, bBh[cur], acc, 0, n0, lane);
            g64(bVt[cur], bKh[cur], acc, 0, n0, lane);
#pragma unroll
            for (int mi = 0; mi < 2; mi++)
#pragma unroll
                for (int ni = 0; ni < 2; ni++)
#pragma unroll
                    for (int rg = 0; rg < 4; rg++) {
                        int m = mi * 16 + (lane >> 4) * 4 + rg;
                        int n = n0 + ni * 16 + (lane & 15);
                        float sn = (acc[mi][ni][rg] + sSf[m * 64 + n]) * sCumL[cur][n];
                        sSf[m * 64 + n] = sn;
                        u16 h = f2bf(sn);
                        sS[m * 64 + n] = h;
                        if (c + 1 < NC) Sin[ub + 4096 + (size_t)(m + half * 32) * 64 + n] = h;
                    }
        }
    }
}

// ---- C: parallel Y = Rhat x Sin^T + PB x SA^T + PK x Vt^T, fused GroupNorm+bonus+gate ----
__global__ __launch_bounds__(256, 1) void k_youtgn(
    const u16* __restrict__ Rhat, const u16* __restrict__ Sin, const u16* __restrict__ PB,
    const u16* __restrict__ SA, const u16* __restrict__ PK, const u16* __restrict__ Vt,
    const u16* __restrict__ rb, const u16* __restrict__ kb, const u16* __restrict__ vb,
    const u16* __restrict__ gb, const float* __restrict__ gn_w, const float* __restrict__ gn_b,
    const float* __restrict__ r_k, u16* __restrict__ yg) {
    __shared__ u16 sR[4096], sSin[4096], sPB[4096], sSA[4096], sPK[4096], sV[4096];
    __shared__ float sY[64 * 66];
    int tid = threadIdx.x, wv = tid >> 6, lane = tid & 63;
    int unit = blockIdx.x;
    int c = unit & 15, bh = unit >> 4, h = bh & 31, b = bh >> 5;
    size_t ub = (size_t)unit * 4096;
    stage8k(Rhat + ub, sR, tid);
    stage8k(Sin + ub, sSin, tid);
    stage8k(PB + ub, sPB, tid);
    stage8k(SA + ub, sSA, tid);
    stage8k(PK + ub, sPK, tid);
    stage8k(Vt + ub, sV, tid);
    __syncthreads();
    int m0 = (wv >> 1) * 32, n0 = (wv & 1) * 32;
    f32x4 acc[2][2] = {};
    g64(sR, sSin, acc, m0, n0, lane);
    g64(sPB, sSA, acc, m0, n0, lane);
    g64(sPK, sV, acc, m0, n0, lane);
#pragma unroll
    for (int mi = 0; mi < 2; mi++)
#pragma unroll
        for (int ni = 0; ni < 2; ni++)
#pragma unroll
            for (int rg = 0; rg < 4; rg++) {
                int m = m0 + mi * 16 + (lane >> 4) * 4 + rg;   // t local
                int n = n0 + ni * 16 + (lane & 15);            // v
                sY[m * 66 + n] = acc[mi][ni][rg];
            }
    __syncthreads();
    // GroupNorm + bonus + gate: wave wv handles t-rows [wv*16, wv*16+16), lane = channel n
    int cg = h * 64 + lane;
    float gwn = gn_w[cg], gbn = gn_b[cg], rkc = r_k[cg];
#pragma unroll 2
    for (int i = 0; i < 16; i++) {
        int t = wv * 16 + i;
        float yv = sY[t * 66 + lane];
        size_t gi = (((size_t)b * 1024 + c * 64 + t) * 32 + h) * 64 + lane;
        float rv = bf2f(rb[gi]), kv = bf2f(kb[gi]);
        float m1 = yv, m2 = yv * yv, s = rv * kv * rkc;
#pragma unroll
        for (int m = 32; m >= 1; m >>= 1) {
            m1 += __shfl_xor(m1, m, 64);
            m2 += __shfl_xor(m2, m, 64);
            s  += __shfl_xor(s, m, 64);
        }
        m1 *= (1.f / 64.f);
        m2 *= (1.f / 64.f);
        float var = m2 - m1 * m1;
        float xn = (yv - m1) * rsqrtf(var + GN_EPS_C) * gwn + gbn;
        float out = (xn + s * bf2f(vb[gi])) * bf2f(gb[gi]);
        yg[gi] = f2bf(out);
    }
}

// ---------------- launcher ----------------
extern "C" void kernel_launch(void* const* d_in, const int* in_sizes, int n_in,
                              void* d_out, int out_size, void* d_ws, size_t ws_size,
                              hipStream_t stream) {
    const float* x      = (const float*)d_in[0];
    const float* vfirst = (const float*)d_in[1];
    const float* x_r = (const float*)d_in[2];
    const float* x_w = (const float*)d_in[3];
    const float* x_k = (const float*)d_in[4];
    const float* x_v = (const float*)d_in[5];
    const float* x_a = (const float*)d_in[6];
    const float* x_g = (const float*)d_in[7];
    const float* w0 = (const float*)d_in[8];
    const float* w1 = (const float*)d_in[9];
    const float* w2 = (const float*)d_in[10];
    const float* a0 = (const float*)d_in[11];
    const float* a1 = (const float*)d_in[12];
    const float* a2 = (const float*)d_in[13];
    const float* v0 = (const float*)d_in[14];
    const float* v1 = (const float*)d_in[15];
    const float* v2 = (const float*)d_in[16];
    const float* g1 = (const float*)d_in[17];
    const float* g2 = (const float*)d_in[18];
    const float* k_k = (const float*)d_in[19];
    const float* k_a = (const float*)d_in[20];
    const float* r_k = (const float*)d_in[21];
    const float* W_r = (const float*)d_in[22];
    const float* W_k = (const float*)d_in[23];
    const float* W_v = (const float*)d_in[24];
    const float* W_o = (const float*)d_in[25];
    const float* gn_w = (const float*)d_in[26];
    const float* gn_b = (const float*)d_in[27];
    (void)in_sizes; (void)n_in; (void)out_size; (void)ws_size;

    char* wsp = (char*)d_ws;
    size_t off = 0;
    auto alloc = [&](size_t bytes) -> char* {
        char* p = wsp + off;
        off += (bytes + 255) & ~(size_t)255;
        return p;
    };
    const size_t MAT = (size_t)BT * C_;  // 4M elements

    u16* WrT = (u16*)alloc(MAT * 2);
    u16* WkT = (u16*)alloc(MAT * 2);
    u16* WvT = (u16*)alloc(MAT * 2);
    u16* WoT = (u16*)alloc(MAT * 2);
    u16* w1T = (u16*)alloc((size_t)128 * 2048 * 2);
    u16* a1T = (u16*)alloc((size_t)128 * 2048 * 2);
    u16* v1T = (u16*)alloc((size_t)128 * 2048 * 2);
    u16* g1T = (u16*)alloc((size_t)256 * 2048 * 2);
    u16* w2T = (u16*)alloc((size_t)2048 * 96 * 2);
    u16* a2T = (u16*)alloc((size_t)2048 * 96 * 2);
    u16* v2T = (u16*)alloc((size_t)2048 * 64 * 2);
    u16* g2T = (u16*)alloc((size_t)2048 * 256 * 2);
    char* xmixR = alloc(6 * MAT * 2);          // 48MB; reused by scan scratch
    u16* xmix = (u16*)xmixR;
    u16* hbuf = (u16*)alloc((size_t)BT * 512 * 2);
    u16* rbuf = (u16*)alloc(MAT * 2);
    u16* kbuf = (u16*)alloc(MAT * 2);
    u16* vbuf = (u16*)alloc(MAT * 2);
    u16* asig = (u16*)alloc(MAT * 2);
    float* lwdec = (float*)alloc(MAT * 4);
    u16* gbuf = (u16*)alloc(MAT * 2);
    u16* ygbuf = (u16*)alloc(MAT * 2);
    const size_t UE = (size_t)UNITS * 4096;
    u16* Ahat  = (u16*)alloc(UE * 2);   // backing store for hp/opart aliases only
    u16* Khat  = (u16*)alloc(UE * 2);
    u16* Rhat  = (u16*)alloc(UE * 2);
    u16* Vt    = (u16*)alloc(UE * 2);
    u16* BhatT = (u16*)alloc(UE * 2);
    u16* KhatT = (u16*)alloc(UE * 2);
    float* cumLg = (float*)alloc((size_t)UNITS * 64 * 4);
    (void)Khat;
    // aliases: PB/PK/G1T/VQM/SA/Sin over xmix (dead after rkvup)
    u16* PB   = (u16*)(xmixR + (size_t)0 * 1024 * 1024);
    u16* PK   = (u16*)(xmixR + (size_t)8 * 1024 * 1024);
    u16* G1T  = (u16*)(xmixR + (size_t)16 * 1024 * 1024);
    u16* VQM  = (u16*)(xmixR + (size_t)24 * 1024 * 1024);
    u16* SAb  = (u16*)(xmixR + (size_t)32 * 1024 * 1024);
    u16* Sin  = (u16*)(xmixR + (size_t)40 * 1024 * 1024);
    // split-K partials for upproj: 4 x 2048x512 f32 = 16MB over Ahat+Khat (dead regions)
    float* hp = (float*)Ahat;
    // o-proj split-K=2 partials: 2 x 2048x2048 f32 = 32MB over Ahat..Vt (dead after k_youtgn)
    float* opart = (float*)Ahat;

    // 1+2) MERGED preprocessing: 4 big transposes + 8 LoRA transposes + token-shift mix
    PreArgs pa;
    pa.big[0] = {W_r, WrT, 2048, 2048};
    pa.big[1] = {W_k, WkT, 2048, 2048};
    pa.big[2] = {W_v, WvT, 2048, 2048};
    pa.big[3] = {W_o, WoT, 2048, 2048};
    pa.sm[0] = {w1, w1T, 2048, 96};
    pa.sm[1] = {a1, a1T, 2048, 96};
    pa.sm[2] = {v1, v1T, 2048, 64};
    pa.sm[3] = {g1, g1T, 2048, 256};
    pa.sm[4] = {w2, w2T, 96, 2048};
    pa.sm[5] = {a2, a2T, 96, 2048};
    pa.sm[6] = {v2, v2T, 64, 2048};
    pa.sm[7] = {g2, g2T, 256, 2048};
    pa.x = x;
    pa.cs[0] = x_r; pa.cs[1] = x_w; pa.cs[2] = x_k;
    pa.cs[3] = x_v; pa.cs[4] = x_a; pa.cs[5] = x_g;
    pa.xmix = xmix;
    k_pre<<<dim3(64, 64, 6), 256, 0, stream>>>(pa);

    // 3+4) MERGED: r/k/v projections + LoRA up-projections (split-K=4 partials)
    k_rkvup<<<dim3(16, 16, 7), 256, 0, stream>>>(xmix, WrT, WkT, WvT, w1T, a1T, v1T, g1T,
                                                 rbuf, kbuf, vbuf, hp);
    k_upred<<<dim3(1024), 256, 0, stream>>>(hp, hbuf);

    // 5) LoRA down-projections
    k_down4<<<dim3(16, 16, 4), 256, 0, stream>>>(hbuf, w2T, a2T, v2T, g2T,
                                                 lwdec, asig, vbuf, gbuf, w0, a0, v0, vfirst);

    // 6) FUSED scan phase A: prep (block-scan cumsum) + chunkops, Ahat/Bhat/Khat LDS-only
    k_prepchunk<<<dim3(UNITS), 256, 0, stream>>>(lwdec, asig, kbuf, rbuf, vbuf, k_k, k_a,
                                                 Rhat, Vt, BhatT, KhatT, cumLg,
                                                 PB, PK, G1T, VQM);

    // 7) sequential phase, row-split: 128 blocks (bh, half)
    k_scanBl<<<dim3(B_ * H_ * 2), 256, 0, stream>>>(G1T, VQM, BhatT, KhatT, Vt, cumLg, SAb, Sin);

    // 8) parallel Y + GroupNorm + bonus + gate (fused)
    k_youtgn<<<dim3(UNITS), 256, 0, stream>>>(Rhat, Sin, PB, SAb, PK, Vt,
                                              rbuf, kbuf, vbuf, gbuf, gn_w, gn_b, r_k, ygbuf);

    // 9) output projection: split-K=2 (512 blocks, K=1024) + deterministic reduce
    k_oproj<<<dim3(16, 16, 2), 256, 0, stream>>>(ygbuf, WoT, opart);
    k_ored<<<dim3(4096), 256, 0, stream>>>(opart, (float*)d_out);
}

// Round 12
// 479.121 us; speedup vs baseline: 1.0478x; 1.0478x over previous
//
#include <hip/hip_runtime.h>
#include <cstdint>
#include <cstddef>

#define DI __device__ __forceinline__

typedef unsigned short u16;

// ---------------- problem constants ----------------
constexpr int B_ = 2, T_ = 1024, C_ = 2048, H_ = 32, N_ = 64;
constexpr int BT = B_ * T_;            // 2048 rows
constexpr float GN_EPS_C = 64e-5f;     // N * 1e-5
constexpr int LCH = 64;                // scan chunk length
constexpr int NC = T_ / LCH;           // 16 chunks
constexpr int UNITS = B_ * H_ * NC;    // 1024 (b,h,chunk) units

// ---------------- small helpers ----------------
DI float bf2f(u16 h) {
    union { unsigned u; float f; } x; x.u = ((unsigned)h) << 16; return x.f;
}
DI u16 f2bf(float f) {
    union { float f; unsigned u; } x; x.f = f;
    unsigned r = (x.u + 0x7fffu + ((x.u >> 16) & 1u)) >> 16;
    return (u16)r;
}
DI float sigmoidf_(float x) { return 1.f / (1.f + __expf(-x)); }
DI float tanhf_(float x) { float e = __expf(2.f * x); return 1.f - 2.f / (e + 1.f); }

typedef __attribute__((ext_vector_type(8))) __bf16 bf16x8;
typedef __attribute__((ext_vector_type(4))) float f32x4;

DI void gload16(const void* g, void* l) {
    __builtin_amdgcn_global_load_lds(
        (const __attribute__((address_space(1))) void*)g,
        (__attribute__((address_space(3))) void*)l,
        16, 0, 0);
}

// ---------------- epilogue ids ----------------
enum { EP_BF16 = 0, EP_F32 = 1, EP_TANH = 2, EP_SIG = 3, EP_LDECAY = 4, EP_ASIG = 5, EP_VMIX = 6 };

// ---------------- deep-K 128x128 bf16 MFMA GEMM core, templated slice count ----------------
// NS=4 (BK=128, 64KB LDS): 16 drains at K=2048 — proven 636 TF on long-K shapes (r4/r11).
// NS=2 (BK=64, 32KB LDS): higher residency — proven better for short-K latency-bound
// kernels (down4, r10 vs r11 A/B). Per-slice [128][32] layout identical in both.
template <int NS>
DI void gemm_core(const u16* __restrict__ A, int lda,
                  const u16* __restrict__ Bt, int ldb,
                  void* __restrict__ Out, int ldc,
                  int Nreal, int K, int m0, int n0, int epi,
                  const float* __restrict__ aux0, const float* __restrict__ aux1) {
    __shared__ u16 lA[NS * 4096];   // NS slices x [128][32]
    __shared__ u16 lB[NS * 4096];
    const int tid = threadIdx.x;
    const int lane = tid & 63;
    const int wv = tid >> 6;
    const int wr = wv >> 1, wc = wv & 1;
    const int r0 = tid >> 2;
    const int cc0 = (tid & 3) * 8;

    f32x4 acc[4][4];
#pragma unroll
    for (int i = 0; i < 4; i++)
#pragma unroll
        for (int j = 0; j < 4; j++) acc[i][j] = (f32x4){0.f, 0.f, 0.f, 0.f};

    const u16* Abase = A + (size_t)(m0 + r0) * lda + cc0;
    const u16* Bbase = Bt + (size_t)(n0 + r0) * ldb + cc0;
    const int stoff = r0 * 32 + cc0;

    for (int k0 = 0; k0 < K; k0 += NS * 32) {
        const int ns = min(NS, (K - k0) >> 5);   // K always a multiple of 32 here
        __syncthreads();
        for (int s = 0; s < ns; s++) {
            const int ko = k0 + s * 32;
            u16* la = lA + s * 4096;
            u16* lb = lB + s * 4096;
            gload16(Abase + ko, la + stoff);
            gload16(Abase + (size_t)64 * lda + ko, la + 2048 + stoff);
            gload16(Bbase + ko, lb + stoff);
            gload16(Bbase + (size_t)64 * ldb + ko, lb + 2048 + stoff);
        }
        __syncthreads();
        for (int s = 0; s < ns; s++) {
            const u16* la = lA + s * 4096;
            const u16* lb = lB + s * 4096;
            bf16x8 af[4], bfr[4];
#pragma unroll
            for (int i = 0; i < 4; i++) {
                af[i]  = *(const bf16x8*)&la[(wr * 64 + i * 16 + (lane & 15)) * 32 + (lane >> 4) * 8];
                bfr[i] = *(const bf16x8*)&lb[(wc * 64 + i * 16 + (lane & 15)) * 32 + (lane >> 4) * 8];
            }
#pragma unroll
            for (int mi = 0; mi < 4; mi++)
#pragma unroll
                for (int ni = 0; ni < 4; ni++)
                    acc[mi][ni] = __builtin_amdgcn_mfma_f32_16x16x32_bf16(af[mi], bfr[ni], acc[mi][ni], 0, 0, 0);
        }
    }

#pragma unroll
    for (int mi = 0; mi < 4; mi++) {
#pragma unroll
        for (int ni = 0; ni < 4; ni++) {
            int n = n0 + wc * 64 + ni * 16 + (lane & 15);
            if (n >= Nreal) continue;
#pragma unroll
            for (int rg = 0; rg < 4; rg++) {
                int m = m0 + wr * 64 + mi * 16 + (lane >> 4) * 4 + rg;
                size_t ix = (size_t)m * ldc + n;
                float f = acc[mi][ni][rg];
                switch (epi) {
                    case EP_BF16: ((u16*)Out)[ix] = f2bf(f); break;
                    case EP_F32:  ((float*)Out)[ix] = f; break;
                    case EP_TANH: ((u16*)Out)[ix] = f2bf(tanhf_(f)); break;
                    case EP_SIG:  ((u16*)Out)[ix] = f2bf(sigmoidf_(f)); break;
                    case EP_LDECAY: {
                        // store LOG of decay: lw = -exp(-0.5 - softplus(-(w0+f)))
                        float z = -(aux0[n] + f);
                        float sp = (z > 15.f) ? z : __logf(1.f + __expf(z));
                        ((float*)Out)[ix] = -__expf(-0.5f - sp);
                    } break;
                    case EP_ASIG: ((u16*)Out)[ix] = f2bf(sigmoidf_(aux0[n] + f)); break;
                    case EP_VMIX: {
                        float vs = sigmoidf_(aux0[n] + f);
                        float old = bf2f(((u16*)Out)[ix]);
                        float vf = aux1[ix];
                        ((u16*)Out)[ix] = f2bf(old + (vf - old) * vs);
                    } break;
                }
            }
        }
    }
}

// ---- merged r/k/v projections + LoRA up-projections (independent work, one dispatch) ----
// BK=128 core: long K chains (2048 / 512) amortize the drains.
__global__ __launch_bounds__(256, 1) void k_rkvup(const u16* xmix,
    const u16* WrT, const u16* WkT, const u16* WvT,
    const u16* w1T, const u16* a1T, const u16* v1T, const u16* g1T,
    u16* rb, u16* kb, u16* vb, float* hp) {
    int z = blockIdx.z;
    if (z < 3) {
        const int sel[3] = {0, 2, 3};  // xr, xk, xv
        const u16* A = xmix + (size_t)sel[z] * BT * C_;
        const u16* Bt = (z == 0) ? WrT : (z == 1) ? WkT : WvT;
        u16* Out = (z == 0) ? rb : (z == 1) ? kb : vb;
        gemm_core<4>(A, C_, Bt, C_, Out, C_, C_, C_, blockIdx.y * 128, blockIdx.x * 128,
                     EP_BF16, nullptr, nullptr);
    } else {
        int zz = z - 3;
        int flat = blockIdx.y * 16 + blockIdx.x;   // 0..255
        const int nact[4] = {64, 64, 64, 128};
        if (flat >= nact[zz]) return;
        int ksp, mb, n0;
        if (zz < 3) { ksp = flat >> 4; mb = flat & 15; n0 = 0; }
        else        { ksp = flat >> 5; int rem = flat & 31; mb = rem >> 1; n0 = (rem & 1) * 128; }
        const int sel[4]   = {1, 4, 3, 5};        // xw, xa, xv, xg
        const int nreal[4] = {96, 96, 64, 256};
        const int coff[4]  = {0, 96, 192, 256};
        const u16* Bt = (zz == 0) ? w1T : (zz == 1) ? a1T : (zz == 2) ? v1T : g1T;
        gemm_core<4>(xmix + (size_t)sel[zz] * BT * C_ + ksp * 512, C_, Bt + ksp * 512, C_,
                     hp + (size_t)ksp * BT * 512 + coff[zz], 512, nreal[zz], 512,
                     mb * 128, n0, EP_F32, nullptr, nullptr);
    }
}

// reduce the 4 split-K partials + apply per-column activation -> hbuf (bf16)
__global__ void k_upred(const float* __restrict__ hp, u16* __restrict__ hbuf) {
    int idx = (blockIdx.x * 256 + threadIdx.x) * 4;   // over 2048*512 elements
    int col = idx & 511;
    const size_t HP = (size_t)BT * 512;
    float4 s = *(const float4*)(hp + idx);
#pragma unroll
    for (int p = 1; p < 4; p++) {
        float4 t = *(const float4*)(hp + p * HP + idx);
        s.x += t.x; s.y += t.y; s.z += t.z; s.w += t.w;
    }
    ushort4 o;
    if (col < 96) {
        o.x = f2bf(tanhf_(s.x)); o.y = f2bf(tanhf_(s.y));
        o.z = f2bf(tanhf_(s.z)); o.w = f2bf(tanhf_(s.w));
    } else if (col < 256) {
        o.x = f2bf(s.x); o.y = f2bf(s.y); o.z = f2bf(s.z); o.w = f2bf(s.w);
    } else {
        o.x = f2bf(sigmoidf_(s.x)); o.y = f2bf(sigmoidf_(s.y));
        o.z = f2bf(sigmoidf_(s.z)); o.w = f2bf(sigmoidf_(s.w));
    }
    *(ushort4*)(hbuf + idx) = o;
}

// ---- fused LoRA down-projections (z 0..3) ----
// BK=64 core: K={96,96,64,256} chains are latency-bound; 32KB LDS keeps residency high
// (r10 vs r11 A/B: the 64KB core cost ~20 us here with no drain-count benefit).
__global__ __launch_bounds__(256, 1) void k_down4(const u16* hbuf, const u16* w2T, const u16* a2T,
                                                  const u16* v2T, const u16* g2T,
                                                  float* lwdec, u16* asig, u16* vbuf, u16* gbuf,
                                                  const float* w0, const float* a0, const float* v0,
                                                  const float* vfirst) {
    int z = blockIdx.z;
    const int Ks[4]   = {96, 96, 64, 256};
    const int coff[4] = {0, 96, 192, 256};
    const int epi[4]  = {EP_LDECAY, EP_ASIG, EP_VMIX, EP_BF16};
    const u16* Bt = (z == 0) ? w2T : (z == 1) ? a2T : (z == 2) ? v2T : g2T;
    void* Out = (z == 0) ? (void*)lwdec : (z == 1) ? (void*)asig : (z == 2) ? (void*)vbuf : (void*)gbuf;
    const float* aux0 = (z == 0) ? w0 : (z == 1) ? a0 : (z == 2) ? v0 : nullptr;
    const float* aux1 = (z == 2) ? vfirst : nullptr;
    gemm_core<2>(hbuf + coff[z], 512, Bt, Ks[z], Out, 2048, 2048, Ks[z],
                 blockIdx.y * 128, blockIdx.x * 128, epi[z], aux0, aux1);
}

// ---- output projection: split-K=2 (512 blocks, K=1024 chains) + deterministic reduce ----
__global__ __launch_bounds__(256, 1) void k_oproj(const u16* yg, const u16* WoT, float* opart) {
    int ksp = blockIdx.z;
    gemm_core<4>(yg + ksp * 1024, 2048, WoT + ksp * 1024, 2048,
                 opart + (size_t)ksp * BT * C_, 2048, 2048, 1024,
                 blockIdx.y * 128, blockIdx.x * 128, EP_F32, nullptr, nullptr);
}

__global__ void k_ored(const float* __restrict__ p, float* __restrict__ out) {
    int idx = (blockIdx.x * 256 + threadIdx.x) * 4;
    const size_t S = (size_t)BT * C_;
    float4 a = *(const float4*)(p + idx);
    float4 b = *(const float4*)(p + S + idx);
    float4 o = {a.x + b.x, a.y + b.y, a.z + b.z, a.w + b.w};
    *(float4*)(out + idx) = o;
}

// ---------------- merged preprocessing: transposes + token-shift mix ----------------
struct TDesc { const float* in; u16* out; int K; int N; };
struct PreArgs {
    TDesc big[4];
    TDesc sm[8];
    const float* x;
    const float* cs[6];
    u16* xmix;
};

DI void transpose_tile(TDesc dd, int k0, int n0, int tidx) {
    __shared__ float tile[32][33];
    int tx = tidx & 31, ty = tidx >> 5;
#pragma unroll
    for (int i = 0; i < 32; i += 8)
        tile[ty + i][tx] = dd.in[(size_t)(k0 + ty + i) * dd.N + (n0 + tx)];
    __syncthreads();
#pragma unroll
    for (int i = 0; i < 32; i += 8)
        dd.out[(size_t)(n0 + ty + i) * dd.K + (k0 + tx)] = f2bf(tile[tx][ty + i]);
}

// grid (64,64,6): z<4 big 2048^2 transposes; z==4 packed small transposes; z==5 mix
__global__ void k_pre(PreArgs a) {
    int z = blockIdx.z;
    if (z < 4) {
        transpose_tile(a.big[z], blockIdx.x * 32, blockIdx.y * 32, threadIdx.x);
        return;
    }
    if (z == 4) {
        int flat = blockIdx.y * 64 + blockIdx.x;
        const int cnt[8] = {192, 192, 128, 512, 192, 192, 128, 512};  // (K/32)*(N/32) per mat
        int d = 0, loc = flat;
        while (d < 8 && loc >= cnt[d]) { loc -= cnt[d]; d++; }
        if (d >= 8) return;
        TDesc dd = a.sm[d];
        int nn = dd.N >> 5;
        transpose_tile(dd, (loc / nn) * 32, (loc % nn) * 32, threadIdx.x);
        return;
    }
    // z == 5: token-shift mix (x4 vectorized)
    int idx = (blockIdx.y * 64 + blockIdx.x) * 256 + threadIdx.x;
    int base = idx * 4;
    int c4 = base & (C_ - 1);
    int bt = base >> 11;
    int t = bt & (T_ - 1);
    float4 xv = *(const float4*)(a.x + base);
    float4 xp = (t == 0) ? (float4){0.f, 0.f, 0.f, 0.f} : *(const float4*)(a.x + base - C_);
    float4 dx = {xp.x - xv.x, xp.y - xv.y, xp.z - xv.z, xp.w - xv.w};
    const size_t S = (size_t)BT * C_;
#pragma unroll
    for (int j = 0; j < 6; j++) {
        float4 cc = *(const float4*)(a.cs[j] + c4);
        ushort4 o;
        o.x = f2bf(xv.x + dx.x * cc.x);
        o.y = f2bf(xv.y + dx.y * cc.y);
        o.z = f2bf(xv.z + dx.z * cc.z);
        o.w = f2bf(xv.w + dx.w * cc.w);
        *(ushort4*)(a.xmix + j * S + base) = o;
    }
}

// ================= chunked WKV7 scan =================
DI bf16x8 frag64(const u16* p, int row, int ks, int lane) {
    return *(const bf16x8*)&p[(row + (lane & 15)) * 64 + ks * 32 + (lane >> 4) * 8];
}

DI void g64(const u16* lA, const u16* lB, f32x4 acc[2][2], int m0, int n0, int lane) {
#pragma unroll
    for (int ks = 0; ks < 2; ks++) {
        bf16x8 a0 = frag64(lA, m0, ks, lane);
        bf16x8 a1 = frag64(lA, m0 + 16, ks, lane);
        bf16x8 b0 = frag64(lB, n0, ks, lane);
        bf16x8 b1 = frag64(lB, n0 + 16, ks, lane);
        acc[0][0] = __builtin_amdgcn_mfma_f32_16x16x32_bf16(a0, b0, acc[0][0], 0, 0, 0);
        acc[0][1] = __builtin_amdgcn_mfma_f32_16x16x32_bf16(a0, b1, acc[0][1], 0, 0, 0);
        acc[1][0] = __builtin_amdgcn_mfma_f32_16x16x32_bf16(a1, b0, acc[1][0], 0, 0, 0);
        acc[1][1] = __builtin_amdgcn_mfma_f32_16x16x32_bf16(a1, b1, acc[1][1], 0, 0, 0);
    }
}

DI void stage8k(const u16* g, u16* l, int tid) {   // 4096 u16 = 8KB
    gload16(g + tid * 8, l + tid * 8);
    gload16(g + 2048 + tid * 8, l + 2048 + tid * 8);
}

// ---- FUSED A1+A2: block-scan decay cumsum + head prep directly into LDS, then
//      U -> inversion -> PB/PK/Qt/VQ -> G1T/VQM. Ahat/Bhat/Khat never touch HBM.
//      NOTE: sV is built [v][t] (transposed) — P4 consumes it exactly like the old
//      k_chunkops consumed the staged GLOBAL Vt (which k_prepA wrote transposed).
__global__ __launch_bounds__(256, 1) void k_prepchunk(
    const float* __restrict__ lwdec, const u16* __restrict__ asig,
    u16* __restrict__ kb, const u16* __restrict__ rb, const u16* __restrict__ vb,
    const float* __restrict__ k_k, const float* __restrict__ k_a,
    u16* __restrict__ Rhat, u16* __restrict__ Vt, u16* __restrict__ BhatT,
    u16* __restrict__ KhatT, float* __restrict__ cumLg,
    u16* __restrict__ PB, u16* __restrict__ PK, u16* __restrict__ G1T, u16* __restrict__ VQM) {
    __shared__ u16 sA[4096], sB[4096], sK[4096], sR[4096], sV[4096], sQt[4096], sAT[4096];
    __shared__ float Uf[64 * 65];
    __shared__ float wsum[4][64];
    int tid = threadIdx.x, wv = tid >> 6, lane = tid & 63;
    int unit = blockIdx.x;
    int c = unit & 15, bh = unit >> 4, h = bh & 31, b = bh >> 5;
    size_t ub = (size_t)unit * 4096;
    int m0 = (wv >> 1) * 32, n0 = (wv & 1) * 32;
    u16* sMt = sB;   // alias: sB dead after P2
    u16* sVQ = sR;   // alias: sR dead after P2

    // ---- P0a: wave-local decay sums (wave wv owns t in [wv*16, wv*16+16)) ----
    int cg = h * 64 + lane;
    float kkc = k_k[cg], kac = k_a[cg];
    int t0 = wv * 16;
    size_t gbase = (((size_t)b * 1024 + c * 64 + t0) * 32 + h) * 64 + lane;  // +2048 per t
    float ls = 0.f;
#pragma unroll
    for (int i = 0; i < 16; i++) ls += lwdec[gbase + (size_t)i * 2048];
    wsum[wv][lane] = ls;
    __syncthreads();
    float cs = 0.f;
    for (int w = 0; w < wv; w++) cs += wsum[w][lane];

    // ---- P0b: head prep (kk-norm, k-mod) + hat vectors into LDS ----
#pragma unroll 4
    for (int i = 0; i < 16; i++) {
        int t = t0 + i;
        size_t gi = gbase + (size_t)i * 2048;
        float lw = lwdec[gi];
        float kraw = bf2f(kb[gi]);
        float ic = bf2f(asig[gi]);
        float r = bf2f(rb[gi]), v = bf2f(vb[gi]);
        float kkv = kraw * kkc;
        float ss = kkv * kkv;
#pragma unroll
        for (int m = 32; m >= 1; m >>= 1) ss += __shfl_xor(ss, m, 64);
        float kk = kkv * (1.f / fmaxf(sqrtf(ss), 1e-12f));
        float kmod = kraw * fmaf(ic - 1.f, kac, 1.f);
        kb[gi] = f2bf(kmod);
        float cum_prev = __expf(cs);   // cs = sum of lw over t' < t
        cs += lw;
        float cum = __expf(cs);
        float inv = __expf(-cs);
        sA[t * 64 + lane] = f2bf(-kk * cum_prev);
        u16 rh_ = f2bf(r * cum);
        sR[t * 64 + lane] = rh_;
        Rhat[ub + t * 64 + lane] = rh_;
        sB[t * 64 + lane] = f2bf(kk * ic * inv);
        sK[t * 64 + lane] = f2bf(kmod * inv);
        sV[lane * 64 + t] = f2bf(v);   // [v][t] — matches old staged-global Vt layout for P4
    }
    if (wv == 3) cumLg[(size_t)unit * 64 + lane] = __expf(cs);
    __syncthreads();

    // ---- global copies for scan/youtgn (waves 0/1/2; wave3 goes straight to P1) ----
    if (wv < 3) {
        if (wv == 2) {
            // sV already [v][t]; straight vector copy to global Vt
            uint4* s = (uint4*)(sV + lane * 64);
            uint4* p = (uint4*)(Vt + ub + lane * 64);
#pragma unroll
            for (int i = 0; i < 8; i++) p[i] = s[i];
        } else {
            const u16* src = (wv == 0) ? sB : sK;
            u16* dst = (wv == 0) ? BhatT : KhatT;
            union U64x { u16 hh[64]; uint4 q[8]; } tm;
#pragma unroll
            for (int t = 0; t < 64; t++) tm.hh[t] = src[t * 64 + lane];
            uint4* p = (uint4*)(dst + ub + lane * 64);
#pragma unroll
            for (int i = 0; i < 8; i++) p[i] = tm.q[i];
        }
    }

    // P1: U[s][t] (strict upper) + AhatT
    {
        f32x4 acc[2][2] = {};
        g64(sB, sA, acc, m0, n0, lane);
#pragma unroll
        for (int mi = 0; mi < 2; mi++)
#pragma unroll
            for (int ni = 0; ni < 2; ni++)
#pragma unroll
                for (int rg = 0; rg < 4; rg++) {
                    int m = m0 + mi * 16 + (lane >> 4) * 4 + rg;   // s
                    int n = n0 + ni * 16 + (lane & 15);            // t
                    Uf[m * 65 + n] = (m < n) ? acc[mi][ni][rg] : 0.f;
                }
#pragma unroll
        for (int i = 0; i < 16; i++) {
            int idx = tid * 16 + i;
            int k = idx >> 6, s = idx & 63;
            sAT[idx] = sA[s * 64 + k];
        }
    }
    __syncthreads();

    // P2: PB, PK (global) + Qt (LDS)
    {
        f32x4 a1[2][2] = {}, a2[2][2] = {}, a3[2][2] = {};
        g64(sR, sB, a1, m0, n0, lane);
        g64(sR, sK, a2, m0, n0, lane);
        g64(sA, sK, a3, m0, n0, lane);
#pragma unroll
        for (int mi = 0; mi < 2; mi++)
#pragma unroll
            for (int ni = 0; ni < 2; ni++)
#pragma unroll
                for (int rg = 0; rg < 4; rg++) {
                    int m = m0 + mi * 16 + (lane >> 4) * 4 + rg;
                    int n = n0 + ni * 16 + (lane & 15);
                    PB[ub + m * 64 + n] = f2bf((n <= m) ? a1[mi][ni][rg] : 0.f);
                    PK[ub + m * 64 + n] = f2bf((n <= m) ? a2[mi][ni][rg] : 0.f);
                    sQt[m * 64 + n] = f2bf((n < m) ? a3[mi][ni][rg] : 0.f);
                }
    }
    __syncthreads();

    // P3: blocked inversion of (I-U), in place in Uf. Blocks 16x16.
    if (lane < 16) {
        int s0 = wv * 16, t = lane;
        Uf[(s0 + 15) * 65 + (s0 + t)] = (t == 15) ? 1.f : 0.f;
        for (int s = 14; s >= 0; s--) {
            float acc = (t == s) ? 1.f : 0.f;
            for (int u = s + 1; u < 16; u++)
                acc += Uf[(s0 + s) * 65 + (s0 + u)] * Uf[(s0 + u) * 65 + (s0 + t)];
            Uf[(s0 + s) * 65 + (s0 + t)] = acc;
        }
    }
    __syncthreads();
    for (int j = 1; j <= 3; j++) {
        float Xn[4];
        int t = lane & 15, q = lane >> 4;
        bool act = (wv < j);
        if (act) {
            int i = wv;
            float Wreg[4];
#pragma unroll
            for (int ri = 0; ri < 4; ri++) {
                int r = q * 4 + ri;
                float w = 0.f;
                for (int p = i; p < j; p++)
#pragma unroll
                    for (int u = 0; u < 16; u++)
                        w += Uf[(i * 16 + r) * 65 + p * 16 + u] * Uf[(p * 16 + u) * 65 + j * 16 + t];
                Wreg[ri] = w;
            }
#pragma unroll
            for (int ri = 0; ri < 4; ri++) {
                float acc = 0.f;
#pragma unroll
                for (int u = 0; u < 16; u++)
                    acc += __shfl(Wreg[ri], (lane & 48) + u, 64) * Uf[(j * 16 + u) * 65 + (j * 16 + t)];
                Xn[ri] = acc;
            }
        }
        __syncthreads();
        if (act) {
#pragma unroll
            for (int ri = 0; ri < 4; ri++)
                Uf[(wv * 16 + q * 4 + ri) * 65 + j * 16 + t] = Xn[ri];
        }
        __syncthreads();
    }
    // sMt[t][s] = X[s][t] (bf16)
#pragma unroll
    for (int i = 0; i < 16; i++) {
        int idx = tid * 16 + i;
        int t = idx >> 6, s = idx & 63;
        sMt[idx] = f2bf((s <= t) ? Uf[s * 65 + t] : 0.f);
    }
    __syncthreads();

    // P4: VQ = Vt x Qt^T -> sVQ  (sV is [v][t], same as old staged-global layout)
    {
        f32x4 acc[2][2] = {};
        g64(sV, sQt, acc, m0, n0, lane);
#pragma unroll
        for (int mi = 0; mi < 2; mi++)
#pragma unroll
            for (int ni = 0; ni < 2; ni++)
#pragma unroll
                for (int rg = 0; rg < 4; rg++) {
                    int m = m0 + mi * 16 + (lane >> 4) * 4 + rg;
                    int n = n0 + ni * 16 + (lane & 15);
                    sVQ[m * 64 + n] = f2bf(acc[mi][ni][rg]);
                }
    }
    __syncthreads();

    // P5: VQM = VQ x X ; G1T[t][k] = sum_s X[s][t] Ahat[s][k]
    {
        f32x4 a1[2][2] = {}, a2[2][2] = {};
        g64(sVQ, sMt, a1, m0, n0, lane);
        g64(sMt, sAT, a2, m0, n0, lane);
#pragma unroll
        for (int mi = 0; mi < 2; mi++)
#pragma unroll
            for (int ni = 0; ni < 2; ni++)
#pragma unroll
                for (int rg = 0; rg < 4; rg++) {
                    int m = m0 + mi * 16 + (lane >> 4) * 4 + rg;
                    int n = n0 + ni * 16 + (lane & 15);
                    VQM[ub + m * 64 + n] = f2bf(a1[mi][ni][rg]);
                    G1T[ub + m * 64 + n] = f2bf(a2[mi][ni][rg]);
                }
    }
}

// ---- B: sequential chunk recurrence, SPLIT over state rows v (fully row-parallel).
//      Block (bh, half) owns rows v in [half*32, half*32+32). 128 blocks (2x CUs vs 64).
//      Shared operands G1T/BhatT/KhatT staged in full; VQM/Vt/S halved.
//      Waves 0,1 compute the 32x64 tile (n0 = wv*32); waves 2,3 only help staging.
//      All __syncthreads() executed uniformly by all 256 threads.
__global__ __launch_bounds__(256, 1) void k_scanBl(
    const u16* __restrict__ G1T, const u16* __restrict__ VQM, const u16* __restrict__ BhatT,
    const u16* __restrict__ KhatT, const u16* __restrict__ Vt, const float* __restrict__ cumLg,
    u16* __restrict__ SA, u16* __restrict__ Sin) {
    __shared__ u16 bG1[2][4096], bBh[2][4096], bKh[2][4096];
    __shared__ u16 bVQ[2][2048], bVt[2][2048];
    __shared__ u16 sSA[2048], sS[2048];
    __shared__ float sSf[2048];
    __shared__ float sCumL[2][64];

    int tid = threadIdx.x, wv = tid >> 6, lane = tid & 63;
    int bh = blockIdx.x >> 1;
    int half = blockIdx.x & 1;
    int hoff = half * 2048;            // element offset of our 32-row half in [64][64] bufs
    int n0 = (wv & 1) * 32;            // waves 0,1: n-halves; waves 2,3 idle in MFMA

    for (int i = tid; i < 2048; i += 256) { sSf[i] = 0.f; sS[i] = 0; }
    {   // Sin chunk 0 = zeros (our half)
        uint4 z = {0, 0, 0, 0};
        uint4* p = (uint4*)(Sin + (size_t)bh * NC * 4096 + hoff);
        for (int i = tid; i < 256; i += 256) p[i] = z;
    }

    auto stage = [&](int c, int buf) {
        size_t ub = ((size_t)bh * NC + c) * 4096;
        stage8k(G1T + ub, bG1[buf], tid);
        stage8k(BhatT + ub, bBh[buf], tid);
        stage8k(KhatT + ub, bKh[buf], tid);
        gload16(VQM + ub + hoff + tid * 8, bVQ[buf] + tid * 8);   // 2048 u16 = 256x16B
        gload16(Vt + ub + hoff + tid * 8, bVt[buf] + tid * 8);
        if (tid < 16) gload16(cumLg + ((size_t)bh * NC + c) * 64 + tid * 4, &sCumL[buf][tid * 4]);
    };

    stage(0, 0);
    for (int c = 0; c < NC; c++) {
        int cur = c & 1;
        __syncthreads();                  // B1: staged data + prev S' visible
        if (c + 1 < NC) stage(c + 1, 1 - cur);
        size_t ub = ((size_t)bh * NC + c) * 4096;

        // gSA: SA = S x G1T-form + VQM   (rows v local 0..32)
        if (wv < 2) {
            f32x4 acc[2][2];
#pragma unroll
            for (int mi = 0; mi < 2; mi++)
#pragma unroll
                for (int ni = 0; ni < 2; ni++)
#pragma unroll
                    for (int rg = 0; rg < 4; rg++) {
                        int m = mi * 16 + (lane >> 4) * 4 + rg;
                        int n = n0 + ni * 16 + (lane & 15);
                        acc[mi][ni][rg] = bf2f(bVQ[cur][m * 64 + n]);
                    }
            g64(sS, bG1[cur], acc, 0, n0, lane);
#pragma unroll
            for (int mi = 0; mi < 2; mi++)
#pragma unroll
                for (int ni = 0; ni < 2; ni++)
#pragma unroll
                    for (int rg = 0; rg < 4; rg++) {
                        int m = mi * 16 + (lane >> 4) * 4 + rg;
                        int n = n0 + ni * 16 + (lane & 15);
                        u16 h = f2bf(acc[mi][ni][rg]);
                        sSA[m * 64 + n] = h;
                        SA[ub + (size_t)(m + half * 32) * 64 + n] = h;
                    }
        }
        __syncthreads();                  // B2 (also drains prefetch)

        // gS': S' = (S + SA.bhat + Vt.khat) * cumL[k]
        if (wv < 2) {
            f32x4 acc[2][2] = {};
            g64(sSA, bBh[cur], acc, 0, n0, lane);
            g64(bVt[cur], bKh[cur], acc, 0, n0, lane);
#pragma unroll
            for (int mi = 0; mi < 2; mi++)
#pragma unroll
                for (int ni = 0; ni < 2; ni++)
#pragma unroll
                    for (int rg = 0; rg < 4; rg++) {
                        int m = mi * 16 + (lane >> 4) * 4 + rg;
                        int n = n0 + ni * 16 + (lane & 15);
                        float sn = (acc[mi][ni][rg] + sSf[m * 64 + n]) * sCumL[cur][n];
                        sSf[m * 64 + n] = sn;
                        u16 h = f2bf(sn);
                        sS[m * 64 + n] = h;
                        if (c + 1 < NC) Sin[ub + 4096 + (size_t)(m + half * 32) * 64 + n] = h;
                    }
        }
    }
}

// ---- C: parallel Y = Rhat x Sin^T + PB x SA^T + PK x Vt^T, fused GroupNorm+bonus+gate ----
__global__ __launch_bounds__(256, 1) void k_youtgn(
    const u16* __restrict__ Rhat, const u16* __restrict__ Sin, const u16* __restrict__ PB,
    const u16* __restrict__ SA, const u16* __restrict__ PK, const u16* __restrict__ Vt,
    const u16* __restrict__ rb, const u16* __restrict__ kb, const u16* __restrict__ vb,
    const u16* __restrict__ gb, const float* __restrict__ gn_w, const float* __restrict__ gn_b,
    const float* __restrict__ r_k, u16* __restrict__ yg) {
    __shared__ u16 sR[4096], sSin[4096], sPB[4096], sSA[4096], sPK[4096], sV[4096];
    __shared__ float sY[64 * 66];
    int tid = threadIdx.x, wv = tid >> 6, lane = tid & 63;
    int unit = blockIdx.x;
    int c = unit & 15, bh = unit >> 4, h = bh & 31, b = bh >> 5;
    size_t ub = (size_t)unit * 4096;
    stage8k(Rhat + ub, sR, tid);
    stage8k(Sin + ub, sSin, tid);
    stage8k(PB + ub, sPB, tid);
    stage8k(SA + ub, sSA, tid);
    stage8k(PK + ub, sPK, tid);
    stage8k(Vt + ub, sV, tid);
    __syncthreads();
    int m0 = (wv >> 1) * 32, n0 = (wv & 1) * 32;
    f32x4 acc[2][2] = {};
    g64(sR, sSin, acc, m0, n0, lane);
    g64(sPB, sSA, acc, m0, n0, lane);
    g64(sPK, sV, acc, m0, n0, lane);
#pragma unroll
    for (int mi = 0; mi < 2; mi++)
#pragma unroll
        for (int ni = 0; ni < 2; ni++)
#pragma unroll
            for (int rg = 0; rg < 4; rg++) {
                int m = m0 + mi * 16 + (lane >> 4) * 4 + rg;   // t local
                int n = n0 + ni * 16 + (lane & 15);            // v
                sY[m * 66 + n] = acc[mi][ni][rg];
            }
    __syncthreads();
    // GroupNorm + bonus + gate: wave wv handles t-rows [wv*16, wv*16+16), lane = channel n
    int cg = h * 64 + lane;
    float gwn = gn_w[cg], gbn = gn_b[cg], rkc = r_k[cg];
#pragma unroll 2
    for (int i = 0; i < 16; i++) {
        int t = wv * 16 + i;
        float yv = sY[t * 66 + lane];
        size_t gi = (((size_t)b * 1024 + c * 64 + t) * 32 + h) * 64 + lane;
        float rv = bf2f(rb[gi]), kv = bf2f(kb[gi]);
        float m1 = yv, m2 = yv * yv, s = rv * kv * rkc;
#pragma unroll
        for (int m = 32; m >= 1; m >>= 1) {
            m1 += __shfl_xor(m1, m, 64);
            m2 += __shfl_xor(m2, m, 64);
            s  += __shfl_xor(s, m, 64);
        }
        m1 *= (1.f / 64.f);
        m2 *= (1.f / 64.f);
        float var = m2 - m1 * m1;
        float xn = (yv - m1) * rsqrtf(var + GN_EPS_C) * gwn + gbn;
        float out = (xn + s * bf2f(vb[gi])) * bf2f(gb[gi]);
        yg[gi] = f2bf(out);
    }
}

// ---------------- launcher ----------------
extern "C" void kernel_launch(void* const* d_in, const int* in_sizes, int n_in,
                              void* d_out, int out_size, void* d_ws, size_t ws_size,
                              hipStream_t stream) {
    const float* x      = (const float*)d_in[0];
    const float* vfirst = (const float*)d_in[1];
    const float* x_r = (const float*)d_in[2];
    const float* x_w = (const float*)d_in[3];
    const float* x_k = (const float*)d_in[4];
    const float* x_v = (const float*)d_in[5];
    const float* x_a = (const float*)d_in[6];
    const float* x_g = (const float*)d_in[7];
    const float* w0 = (const float*)d_in[8];
    const float* w1 = (const float*)d_in[9];
    const float* w2 = (const float*)d_in[10];
    const float* a0 = (const float*)d_in[11];
    const float* a1 = (const float*)d_in[12];
    const float* a2 = (const float*)d_in[13];
    const float* v0 = (const float*)d_in[14];
    const float* v1 = (const float*)d_in[15];
    const float* v2 = (const float*)d_in[16];
    const float* g1 = (const float*)d_in[17];
    const float* g2 = (const float*)d_in[18];
    const float* k_k = (const float*)d_in[19];
    const float* k_a = (const float*)d_in[20];
    const float* r_k = (const float*)d_in[21];
    const float* W_r = (const float*)d_in[22];
    const float* W_k = (const float*)d_in[23];
    const float* W_v = (const float*)d_in[24];
    const float* W_o = (const float*)d_in[25];
    const float* gn_w = (const float*)d_in[26];
    const float* gn_b = (const float*)d_in[27];
    (void)in_sizes; (void)n_in; (void)out_size; (void)ws_size;

    char* wsp = (char*)d_ws;
    size_t off = 0;
    auto alloc = [&](size_t bytes) -> char* {
        char* p = wsp + off;
        off += (bytes + 255) & ~(size_t)255;
        return p;
    };
    const size_t MAT = (size_t)BT * C_;  // 4M elements

    u16* WrT = (u16*)alloc(MAT * 2);
    u16* WkT = (u16*)alloc(MAT * 2);
    u16* WvT = (u16*)alloc(MAT * 2);
    u16* WoT = (u16*)alloc(MAT * 2);
    u16* w1T = (u16*)alloc((size_t)128 * 2048 * 2);
    u16* a1T = (u16*)alloc((size_t)128 * 2048 * 2);
    u16* v1T = (u16*)alloc((size_t)128 * 2048 * 2);
    u16* g1T = (u16*)alloc((size_t)256 * 2048 * 2);
    u16* w2T = (u16*)alloc((size_t)2048 * 96 * 2);
    u16* a2T = (u16*)alloc((size_t)2048 * 96 * 2);
    u16* v2T = (u16*)alloc((size_t)2048 * 64 * 2);
    u16* g2T = (u16*)alloc((size_t)2048 * 256 * 2);
    char* xmixR = alloc(6 * MAT * 2);          // 48MB; reused by scan scratch
    u16* xmix = (u16*)xmixR;
    u16* hbuf = (u16*)alloc((size_t)BT * 512 * 2);
    u16* rbuf = (u16*)alloc(MAT * 2);
    u16* kbuf = (u16*)alloc(MAT * 2);
    u16* vbuf = (u16*)alloc(MAT * 2);
    u16* asig = (u16*)alloc(MAT * 2);
    float* lwdec = (float*)alloc(MAT * 4);
    u16* gbuf = (u16*)alloc(MAT * 2);
    u16* ygbuf = (u16*)alloc(MAT * 2);
    const size_t UE = (size_t)UNITS * 4096;
    u16* Ahat  = (u16*)alloc(UE * 2);   // backing store for hp/opart aliases only
    u16* Khat  = (u16*)alloc(UE * 2);
    u16* Rhat  = (u16*)alloc(UE * 2);
    u16* Vt    = (u16*)alloc(UE * 2);
    u16* BhatT = (u16*)alloc(UE * 2);
    u16* KhatT = (u16*)alloc(UE * 2);
    float* cumLg = (float*)alloc((size_t)UNITS * 64 * 4);
    (void)Khat;
    // aliases: PB/PK/G1T/VQM/SA/Sin over xmix (dead after rkvup)
    u16* PB   = (u16*)(xmixR + (size_t)0 * 1024 * 1024);
    u16* PK   = (u16*)(xmixR + (size_t)8 * 1024 * 1024);
    u16* G1T  = (u16*)(xmixR + (size_t)16 * 1024 * 1024);
    u16* VQM  = (u16*)(xmixR + (size_t)24 * 1024 * 1024);
    u16* SAb  = (u16*)(xmixR + (size_t)32 * 1024 * 1024);
    u16* Sin  = (u16*)(xmixR + (size_t)40 * 1024 * 1024);
    // split-K partials for upproj: 4 x 2048x512 f32 = 16MB over Ahat+Khat (dead regions)
    float* hp = (float*)Ahat;
    // o-proj split-K=2 partials: 2 x 2048x2048 f32 = 32MB over Ahat..Vt (dead after k_youtgn)
    float* opart = (float*)Ahat;

    // 1+2) MERGED preprocessing: 4 big transposes + 8 LoRA transposes + token-shift mix
    PreArgs pa;
    pa.big[0] = {W_r, WrT, 2048, 2048};
    pa.big[1] = {W_k, WkT, 2048, 2048};
    pa.big[2] = {W_v, WvT, 2048, 2048};
    pa.big[3] = {W_o, WoT, 2048, 2048};
    pa.sm[0] = {w1, w1T, 2048, 96};
    pa.sm[1] = {a1, a1T, 2048, 96};
    pa.sm[2] = {v1, v1T, 2048, 64};
    pa.sm[3] = {g1, g1T, 2048, 256};
    pa.sm[4] = {w2, w2T, 96, 2048};
    pa.sm[5] = {a2, a2T, 96, 2048};
    pa.sm[6] = {v2, v2T, 64, 2048};
    pa.sm[7] = {g2, g2T, 256, 2048};
    pa.x = x;
    pa.cs[0] = x_r; pa.cs[1] = x_w; pa.cs[2] = x_k;
    pa.cs[3] = x_v; pa.cs[4] = x_a; pa.cs[5] = x_g;
    pa.xmix = xmix;
    k_pre<<<dim3(64, 64, 6), 256, 0, stream>>>(pa);

    // 3+4) MERGED: r/k/v projections + LoRA up-projections (split-K=4 partials; BK=128 core)
    k_rkvup<<<dim3(16, 16, 7), 256, 0, stream>>>(xmix, WrT, WkT, WvT, w1T, a1T, v1T, g1T,
                                                 rbuf, kbuf, vbuf, hp);
    k_upred<<<dim3(1024), 256, 0, stream>>>(hp, hbuf);

    // 5) LoRA down-projections (BK=64 core: residency over drain-amortization at short K)
    k_down4<<<dim3(16, 16, 4), 256, 0, stream>>>(hbuf, w2T, a2T, v2T, g2T,
                                                 lwdec, asig, vbuf, gbuf, w0, a0, v0, vfirst);

    // 6) FUSED scan phase A: prep (block-scan cumsum) + chunkops, Ahat/Bhat/Khat LDS-only
    k_prepchunk<<<dim3(UNITS), 256, 0, stream>>>(lwdec, asig, kbuf, rbuf, vbuf, k_k, k_a,
                                                 Rhat, Vt, BhatT, KhatT, cumLg,
                                                 PB, PK, G1T, VQM);

    // 7) sequential phase, row-split: 128 blocks (bh, half)
    k_scanBl<<<dim3(B_ * H_ * 2), 256, 0, stream>>>(G1T, VQM, BhatT, KhatT, Vt, cumLg, SAb, Sin);

    // 8) parallel Y + GroupNorm + bonus + gate (fused)
    k_youtgn<<<dim3(UNITS), 256, 0, stream>>>(Rhat, Sin, PB, SAb, PK, Vt,
                                              rbuf, kbuf, vbuf, gbuf, gn_w, gn_b, r_k, ygbuf);

    // 9) output projection: split-K=2 (512 blocks, K=1024, BK=128 core) + reduce
    k_oproj<<<dim3(16, 16, 2), 256, 0, stream>>>(ygbuf, WoT, opart);
    k_ored<<<dim3(4096), 256, 0, stream>>>(opart, (float*)d_out);
}

// Round 13
// 471.826 us; speedup vs baseline: 1.0640x; 1.0155x over previous
//
#include <hip/hip_runtime.h>
#include <cstdint>
#include <cstddef>

#define DI __device__ __forceinline__

typedef unsigned short u16;

// ---------------- problem constants ----------------
constexpr int B_ = 2, T_ = 1024, C_ = 2048, H_ = 32, N_ = 64;
constexpr int BT = B_ * T_;            // 2048 rows
constexpr float GN_EPS_C = 64e-5f;     // N * 1e-5
constexpr int LCH = 64;                // scan chunk length
constexpr int NC = T_ / LCH;           // 16 chunks
constexpr int UNITS = B_ * H_ * NC;    // 1024 (b,h,chunk) units

// ---------------- small helpers ----------------
DI float bf2f(u16 h) {
    union { unsigned u; float f; } x; x.u = ((unsigned)h) << 16; return x.f;
}
DI u16 f2bf(float f) {
    union { float f; unsigned u; } x; x.f = f;
    unsigned r = (x.u + 0x7fffu + ((x.u >> 16) & 1u)) >> 16;
    return (u16)r;
}
DI float sigmoidf_(float x) { return 1.f / (1.f + __expf(-x)); }
DI float tanhf_(float x) { float e = __expf(2.f * x); return 1.f - 2.f / (e + 1.f); }

typedef __attribute__((ext_vector_type(8))) __bf16 bf16x8;
typedef __attribute__((ext_vector_type(4))) float f32x4;

DI void gload16(const void* g, void* l) {
    __builtin_amdgcn_global_load_lds(
        (const __attribute__((address_space(1))) void*)g,
        (__attribute__((address_space(3))) void*)l,
        16, 0, 0);
}

// ---------------- epilogue ids ----------------
enum { EP_BF16 = 0, EP_F32 = 1, EP_TANH = 2, EP_SIG = 3, EP_LDECAY = 4, EP_ASIG = 5, EP_VMIX = 6 };

// ---------------- deep-K 128x128 bf16 MFMA GEMM core, templated slice count ----------------
// NS=4 (BK=128, 64KB LDS): long-K chains (r4/r11). NS=2 (BK=64, 32KB): short-K residency (r10/r12).
template <int NS>
DI void gemm_core(const u16* __restrict__ A, int lda,
                  const u16* __restrict__ Bt, int ldb,
                  void* __restrict__ Out, int ldc,
                  int Nreal, int K, int m0, int n0, int epi,
                  const float* __restrict__ aux0, const float* __restrict__ aux1) {
    __shared__ u16 lA[NS * 4096];   // NS slices x [128][32]
    __shared__ u16 lB[NS * 4096];
    const int tid = threadIdx.x;
    const int lane = tid & 63;
    const int wv = tid >> 6;
    const int wr = wv >> 1, wc = wv & 1;
    const int r0 = tid >> 2;
    const int cc0 = (tid & 3) * 8;

    f32x4 acc[4][4];
#pragma unroll
    for (int i = 0; i < 4; i++)
#pragma unroll
        for (int j = 0; j < 4; j++) acc[i][j] = (f32x4){0.f, 0.f, 0.f, 0.f};

    const u16* Abase = A + (size_t)(m0 + r0) * lda + cc0;
    const u16* Bbase = Bt + (size_t)(n0 + r0) * ldb + cc0;
    const int stoff = r0 * 32 + cc0;

    for (int k0 = 0; k0 < K; k0 += NS * 32) {
        const int ns = min(NS, (K - k0) >> 5);   // K always a multiple of 32 here
        __syncthreads();
        for (int s = 0; s < ns; s++) {
            const int ko = k0 + s * 32;
            u16* la = lA + s * 4096;
            u16* lb = lB + s * 4096;
            gload16(Abase + ko, la + stoff);
            gload16(Abase + (size_t)64 * lda + ko, la + 2048 + stoff);
            gload16(Bbase + ko, lb + stoff);
            gload16(Bbase + (size_t)64 * ldb + ko, lb + 2048 + stoff);
        }
        __syncthreads();
        for (int s = 0; s < ns; s++) {
            const u16* la = lA + s * 4096;
            const u16* lb = lB + s * 4096;
            bf16x8 af[4], bfr[4];
#pragma unroll
            for (int i = 0; i < 4; i++) {
                af[i]  = *(const bf16x8*)&la[(wr * 64 + i * 16 + (lane & 15)) * 32 + (lane >> 4) * 8];
                bfr[i] = *(const bf16x8*)&lb[(wc * 64 + i * 16 + (lane & 15)) * 32 + (lane >> 4) * 8];
            }
#pragma unroll
            for (int mi = 0; mi < 4; mi++)
#pragma unroll
                for (int ni = 0; ni < 4; ni++)
                    acc[mi][ni] = __builtin_amdgcn_mfma_f32_16x16x32_bf16(af[mi], bfr[ni], acc[mi][ni], 0, 0, 0);
        }
    }

#pragma unroll
    for (int mi = 0; mi < 4; mi++) {
#pragma unroll
        for (int ni = 0; ni < 4; ni++) {
            int n = n0 + wc * 64 + ni * 16 + (lane & 15);
            if (n >= Nreal) continue;
#pragma unroll
            for (int rg = 0; rg < 4; rg++) {
                int m = m0 + wr * 64 + mi * 16 + (lane >> 4) * 4 + rg;
                size_t ix = (size_t)m * ldc + n;
                float f = acc[mi][ni][rg];
                switch (epi) {
                    case EP_BF16: ((u16*)Out)[ix] = f2bf(f); break;
                    case EP_F32:  ((float*)Out)[ix] = f; break;
                    case EP_TANH: ((u16*)Out)[ix] = f2bf(tanhf_(f)); break;
                    case EP_SIG:  ((u16*)Out)[ix] = f2bf(sigmoidf_(f)); break;
                    case EP_LDECAY: {
                        // store LOG of decay: lw = -exp(-0.5 - softplus(-(w0+f)))
                        float z = -(aux0[n] + f);
                        float sp = (z > 15.f) ? z : __logf(1.f + __expf(z));
                        ((float*)Out)[ix] = -__expf(-0.5f - sp);
                    } break;
                    case EP_ASIG: ((u16*)Out)[ix] = f2bf(sigmoidf_(aux0[n] + f)); break;
                    case EP_VMIX: {
                        float vs = sigmoidf_(aux0[n] + f);
                        float old = bf2f(((u16*)Out)[ix]);
                        float vf = aux1[ix];
                        ((u16*)Out)[ix] = f2bf(old + (vf - old) * vs);
                    } break;
                }
            }
        }
    }
}

// ---- merged r/k/v projections + LoRA up-projections (independent work, one dispatch) ----
__global__ __launch_bounds__(256, 1) void k_rkvup(const u16* xmix,
    const u16* WrT, const u16* WkT, const u16* WvT,
    const u16* w1T, const u16* a1T, const u16* v1T, const u16* g1T,
    u16* rb, u16* kb, u16* vb, float* hp) {
    int z = blockIdx.z;
    if (z < 3) {
        const int sel[3] = {0, 2, 3};  // xr, xk, xv
        const u16* A = xmix + (size_t)sel[z] * BT * C_;
        const u16* Bt = (z == 0) ? WrT : (z == 1) ? WkT : WvT;
        u16* Out = (z == 0) ? rb : (z == 1) ? kb : vb;
        gemm_core<4>(A, C_, Bt, C_, Out, C_, C_, C_, blockIdx.y * 128, blockIdx.x * 128,
                     EP_BF16, nullptr, nullptr);
    } else {
        int zz = z - 3;
        int flat = blockIdx.y * 16 + blockIdx.x;   // 0..255
        const int nact[4] = {64, 64, 64, 128};
        if (flat >= nact[zz]) return;
        int ksp, mb, n0;
        if (zz < 3) { ksp = flat >> 4; mb = flat & 15; n0 = 0; }
        else        { ksp = flat >> 5; int rem = flat & 31; mb = rem >> 1; n0 = (rem & 1) * 128; }
        const int sel[4]   = {1, 4, 3, 5};        // xw, xa, xv, xg
        const int nreal[4] = {96, 96, 64, 256};
        const int coff[4]  = {0, 96, 192, 256};
        const u16* Bt = (zz == 0) ? w1T : (zz == 1) ? a1T : (zz == 2) ? v1T : g1T;
        gemm_core<4>(xmix + (size_t)sel[zz] * BT * C_ + ksp * 512, C_, Bt + ksp * 512, C_,
                     hp + (size_t)ksp * BT * 512 + coff[zz], 512, nreal[zz], 512,
                     mb * 128, n0, EP_F32, nullptr, nullptr);
    }
}

// reduce the 4 split-K partials + apply per-column activation -> hbuf (bf16)
__global__ void k_upred(const float* __restrict__ hp, u16* __restrict__ hbuf) {
    int idx = (blockIdx.x * 256 + threadIdx.x) * 4;   // over 2048*512 elements
    int col = idx & 511;
    const size_t HP = (size_t)BT * 512;
    float4 s = *(const float4*)(hp + idx);
#pragma unroll
    for (int p = 1; p < 4; p++) {
        float4 t = *(const float4*)(hp + p * HP + idx);
        s.x += t.x; s.y += t.y; s.z += t.z; s.w += t.w;
    }
    ushort4 o;
    if (col < 96) {
        o.x = f2bf(tanhf_(s.x)); o.y = f2bf(tanhf_(s.y));
        o.z = f2bf(tanhf_(s.z)); o.w = f2bf(tanhf_(s.w));
    } else if (col < 256) {
        o.x = f2bf(s.x); o.y = f2bf(s.y); o.z = f2bf(s.z); o.w = f2bf(s.w);
    } else {
        o.x = f2bf(sigmoidf_(s.x)); o.y = f2bf(sigmoidf_(s.y));
        o.z = f2bf(sigmoidf_(s.z)); o.w = f2bf(sigmoidf_(s.w));
    }
    *(ushort4*)(hbuf + idx) = o;
}

// ---- fused LoRA down-projections (z 0..3), BK=64 core ----
__global__ __launch_bounds__(256, 1) void k_down4(const u16* hbuf, const u16* w2T, const u16* a2T,
                                                  const u16* v2T, const u16* g2T,
                                                  float* lwdec, u16* asig, u16* vbuf, u16* gbuf,
                                                  const float* w0, const float* a0, const float* v0,
                                                  const float* vfirst) {
    int z = blockIdx.z;
    const int Ks[4]   = {96, 96, 64, 256};
    const int coff[4] = {0, 96, 192, 256};
    const int epi[4]  = {EP_LDECAY, EP_ASIG, EP_VMIX, EP_BF16};
    const u16* Bt = (z == 0) ? w2T : (z == 1) ? a2T : (z == 2) ? v2T : g2T;
    void* Out = (z == 0) ? (void*)lwdec : (z == 1) ? (void*)asig : (z == 2) ? (void*)vbuf : (void*)gbuf;
    const float* aux0 = (z == 0) ? w0 : (z == 1) ? a0 : (z == 2) ? v0 : nullptr;
    const float* aux1 = (z == 2) ? vfirst : nullptr;
    gemm_core<2>(hbuf + coff[z], 512, Bt, Ks[z], Out, 2048, 2048, Ks[z],
                 blockIdx.y * 128, blockIdx.x * 128, epi[z], aux0, aux1);
}

// ---- output projection: split-K=2 (512 blocks, K=1024 chains) + deterministic reduce ----
__global__ __launch_bounds__(256, 1) void k_oproj(const u16* yg, const u16* WoT, float* opart) {
    int ksp = blockIdx.z;
    gemm_core<4>(yg + ksp * 1024, 2048, WoT + ksp * 1024, 2048,
                 opart + (size_t)ksp * BT * C_, 2048, 2048, 1024,
                 blockIdx.y * 128, blockIdx.x * 128, EP_F32, nullptr, nullptr);
}

__global__ void k_ored(const float* __restrict__ p, float* __restrict__ out) {
    int idx = (blockIdx.x * 256 + threadIdx.x) * 4;
    const size_t S = (size_t)BT * C_;
    float4 a = *(const float4*)(p + idx);
    float4 b = *(const float4*)(p + S + idx);
    float4 o = {a.x + b.x, a.y + b.y, a.z + b.z, a.w + b.w};
    *(float4*)(out + idx) = o;
}

// ---------------- merged preprocessing: transposes + token-shift mix ----------------
struct TDesc { const float* in; u16* out; int K; int N; };
struct PreArgs {
    TDesc big[4];
    TDesc sm[8];
    const float* x;
    const float* cs[6];
    u16* xmix;
};

DI void transpose_tile(TDesc dd, int k0, int n0, int tidx) {
    __shared__ float tile[32][33];
    int tx = tidx & 31, ty = tidx >> 5;
#pragma unroll
    for (int i = 0; i < 32; i += 8)
        tile[ty + i][tx] = dd.in[(size_t)(k0 + ty + i) * dd.N + (n0 + tx)];
    __syncthreads();
#pragma unroll
    for (int i = 0; i < 32; i += 8)
        dd.out[(size_t)(n0 + ty + i) * dd.K + (k0 + tx)] = f2bf(tile[tx][ty + i]);
}

// grid (64,64,6): z<4 big 2048^2 transposes; z==4 packed small transposes; z==5 mix
__global__ void k_pre(PreArgs a) {
    int z = blockIdx.z;
    if (z < 4) {
        transpose_tile(a.big[z], blockIdx.x * 32, blockIdx.y * 32, threadIdx.x);
        return;
    }
    if (z == 4) {
        int flat = blockIdx.y * 64 + blockIdx.x;
        const int cnt[8] = {192, 192, 128, 512, 192, 192, 128, 512};  // (K/32)*(N/32) per mat
        int d = 0, loc = flat;
        while (d < 8 && loc >= cnt[d]) { loc -= cnt[d]; d++; }
        if (d >= 8) return;
        TDesc dd = a.sm[d];
        int nn = dd.N >> 5;
        transpose_tile(dd, (loc / nn) * 32, (loc % nn) * 32, threadIdx.x);
        return;
    }
    // z == 5: token-shift mix (x4 vectorized)
    int idx = (blockIdx.y * 64 + blockIdx.x) * 256 + threadIdx.x;
    int base = idx * 4;
    int c4 = base & (C_ - 1);
    int bt = base >> 11;
    int t = bt & (T_ - 1);
    float4 xv = *(const float4*)(a.x + base);
    float4 xp = (t == 0) ? (float4){0.f, 0.f, 0.f, 0.f} : *(const float4*)(a.x + base - C_);
    float4 dx = {xp.x - xv.x, xp.y - xv.y, xp.z - xv.z, xp.w - xv.w};
    const size_t S = (size_t)BT * C_;
#pragma unroll
    for (int j = 0; j < 6; j++) {
        float4 cc = *(const float4*)(a.cs[j] + c4);
        ushort4 o;
        o.x = f2bf(xv.x + dx.x * cc.x);
        o.y = f2bf(xv.y + dx.y * cc.y);
        o.z = f2bf(xv.z + dx.z * cc.z);
        o.w = f2bf(xv.w + dx.w * cc.w);
        *(ushort4*)(a.xmix + j * S + base) = o;
    }
}

// ================= chunked WKV7 scan =================
DI bf16x8 frag64(const u16* p, int row, int ks, int lane) {
    return *(const bf16x8*)&p[(row + (lane & 15)) * 64 + ks * 32 + (lane >> 4) * 8];
}

DI void g64(const u16* lA, const u16* lB, f32x4 acc[2][2], int m0, int n0, int lane) {
#pragma unroll
    for (int ks = 0; ks < 2; ks++) {
        bf16x8 a0 = frag64(lA, m0, ks, lane);
        bf16x8 a1 = frag64(lA, m0 + 16, ks, lane);
        bf16x8 b0 = frag64(lB, n0, ks, lane);
        bf16x8 b1 = frag64(lB, n0 + 16, ks, lane);
        acc[0][0] = __builtin_amdgcn_mfma_f32_16x16x32_bf16(a0, b0, acc[0][0], 0, 0, 0);
        acc[0][1] = __builtin_amdgcn_mfma_f32_16x16x32_bf16(a0, b1, acc[0][1], 0, 0, 0);
        acc[1][0] = __builtin_amdgcn_mfma_f32_16x16x32_bf16(a1, b0, acc[1][0], 0, 0, 0);
        acc[1][1] = __builtin_amdgcn_mfma_f32_16x16x32_bf16(a1, b1, acc[1][1], 0, 0, 0);
    }
}

DI void stage8k(const u16* g, u16* l, int tid) {   // 4096 u16 = 8KB
    gload16(g + tid * 8, l + tid * 8);
    gload16(g + 2048 + tid * 8, l + 2048 + tid * 8);
}

// ---- FUSED A1+A2 (unchanged from r12) ----
__global__ __launch_bounds__(256, 1) void k_prepchunk(
    const float* __restrict__ lwdec, const u16* __restrict__ asig,
    u16* __restrict__ kb, const u16* __restrict__ rb, const u16* __restrict__ vb,
    const float* __restrict__ k_k, const float* __restrict__ k_a,
    u16* __restrict__ Rhat, u16* __restrict__ Vt, u16* __restrict__ BhatT,
    u16* __restrict__ KhatT, float* __restrict__ cumLg,
    u16* __restrict__ PB, u16* __restrict__ PK, u16* __restrict__ G1T, u16* __restrict__ VQM) {
    __shared__ u16 sA[4096], sB[4096], sK[4096], sR[4096], sV[4096], sQt[4096], sAT[4096];
    __shared__ float Uf[64 * 65];
    __shared__ float wsum[4][64];
    int tid = threadIdx.x, wv = tid >> 6, lane = tid & 63;
    int unit = blockIdx.x;
    int c = unit & 15, bh = unit >> 4, h = bh & 31, b = bh >> 5;
    size_t ub = (size_t)unit * 4096;
    int m0 = (wv >> 1) * 32, n0 = (wv & 1) * 32;
    u16* sMt = sB;   // alias: sB dead after P2
    u16* sVQ = sR;   // alias: sR dead after P2

    // ---- P0a: wave-local decay sums (wave wv owns t in [wv*16, wv*16+16)) ----
    int cg = h * 64 + lane;
    float kkc = k_k[cg], kac = k_a[cg];
    int t0 = wv * 16;
    size_t gbase = (((size_t)b * 1024 + c * 64 + t0) * 32 + h) * 64 + lane;  // +2048 per t
    float ls = 0.f;
#pragma unroll
    for (int i = 0; i < 16; i++) ls += lwdec[gbase + (size_t)i * 2048];
    wsum[wv][lane] = ls;
    __syncthreads();
    float cs = 0.f;
    for (int w = 0; w < wv; w++) cs += wsum[w][lane];

    // ---- P0b: head prep (kk-norm, k-mod) + hat vectors into LDS ----
#pragma unroll 4
    for (int i = 0; i < 16; i++) {
        int t = t0 + i;
        size_t gi = gbase + (size_t)i * 2048;
        float lw = lwdec[gi];
        float kraw = bf2f(kb[gi]);
        float ic = bf2f(asig[gi]);
        float r = bf2f(rb[gi]), v = bf2f(vb[gi]);
        float kkv = kraw * kkc;
        float ss = kkv * kkv;
#pragma unroll
        for (int m = 32; m >= 1; m >>= 1) ss += __shfl_xor(ss, m, 64);
        float kk = kkv * (1.f / fmaxf(sqrtf(ss), 1e-12f));
        float kmod = kraw * fmaf(ic - 1.f, kac, 1.f);
        kb[gi] = f2bf(kmod);
        float cum_prev = __expf(cs);   // cs = sum of lw over t' < t
        cs += lw;
        float cum = __expf(cs);
        float inv = __expf(-cs);
        sA[t * 64 + lane] = f2bf(-kk * cum_prev);
        u16 rh_ = f2bf(r * cum);
        sR[t * 64 + lane] = rh_;
        Rhat[ub + t * 64 + lane] = rh_;
        sB[t * 64 + lane] = f2bf(kk * ic * inv);
        sK[t * 64 + lane] = f2bf(kmod * inv);
        sV[lane * 64 + t] = f2bf(v);   // [v][t] — matches old staged-global Vt layout for P4
    }
    if (wv == 3) cumLg[(size_t)unit * 64 + lane] = __expf(cs);
    __syncthreads();

    // ---- global copies for scan (waves 0/1/2; wave3 goes straight to P1) ----
    if (wv < 3) {
        if (wv == 2) {
            uint4* s = (uint4*)(sV + lane * 64);
            uint4* p = (uint4*)(Vt + ub + lane * 64);
#pragma unroll
            for (int i = 0; i < 8; i++) p[i] = s[i];
        } else {
            const u16* src = (wv == 0) ? sB : sK;
            u16* dst = (wv == 0) ? BhatT : KhatT;
            union U64x { u16 hh[64]; uint4 q[8]; } tm;
#pragma unroll
            for (int t = 0; t < 64; t++) tm.hh[t] = src[t * 64 + lane];
            uint4* p = (uint4*)(dst + ub + lane * 64);
#pragma unroll
            for (int i = 0; i < 8; i++) p[i] = tm.q[i];
        }
    }

    // P1: U[s][t] (strict upper) + AhatT
    {
        f32x4 acc[2][2] = {};
        g64(sB, sA, acc, m0, n0, lane);
#pragma unroll
        for (int mi = 0; mi < 2; mi++)
#pragma unroll
            for (int ni = 0; ni < 2; ni++)
#pragma unroll
                for (int rg = 0; rg < 4; rg++) {
                    int m = m0 + mi * 16 + (lane >> 4) * 4 + rg;   // s
                    int n = n0 + ni * 16 + (lane & 15);            // t
                    Uf[m * 65 + n] = (m < n) ? acc[mi][ni][rg] : 0.f;
                }
#pragma unroll
        for (int i = 0; i < 16; i++) {
            int idx = tid * 16 + i;
            int k = idx >> 6, s = idx & 63;
            sAT[idx] = sA[s * 64 + k];
        }
    }
    __syncthreads();

    // P2: PB, PK (global) + Qt (LDS)
    {
        f32x4 a1[2][2] = {}, a2[2][2] = {}, a3[2][2] = {};
        g64(sR, sB, a1, m0, n0, lane);
        g64(sR, sK, a2, m0, n0, lane);
        g64(sA, sK, a3, m0, n0, lane);
#pragma unroll
        for (int mi = 0; mi < 2; mi++)
#pragma unroll
            for (int ni = 0; ni < 2; ni++)
#pragma unroll
                for (int rg = 0; rg < 4; rg++) {
                    int m = m0 + mi * 16 + (lane >> 4) * 4 + rg;
                    int n = n0 + ni * 16 + (lane & 15);
                    PB[ub + m * 64 + n] = f2bf((n <= m) ? a1[mi][ni][rg] : 0.f);
                    PK[ub + m * 64 + n] = f2bf((n <= m) ? a2[mi][ni][rg] : 0.f);
                    sQt[m * 64 + n] = f2bf((n < m) ? a3[mi][ni][rg] : 0.f);
                }
    }
    __syncthreads();

    // P3: blocked inversion of (I-U), in place in Uf. Blocks 16x16.
    if (lane < 16) {
        int s0 = wv * 16, t = lane;
        Uf[(s0 + 15) * 65 + (s0 + t)] = (t == 15) ? 1.f : 0.f;
        for (int s = 14; s >= 0; s--) {
            float acc = (t == s) ? 1.f : 0.f;
            for (int u = s + 1; u < 16; u++)
                acc += Uf[(s0 + s) * 65 + (s0 + u)] * Uf[(s0 + u) * 65 + (s0 + t)];
            Uf[(s0 + s) * 65 + (s0 + t)] = acc;
        }
    }
    __syncthreads();
    for (int j = 1; j <= 3; j++) {
        float Xn[4];
        int t = lane & 15, q = lane >> 4;
        bool act = (wv < j);
        if (act) {
            int i = wv;
            float Wreg[4];
#pragma unroll
            for (int ri = 0; ri < 4; ri++) {
                int r = q * 4 + ri;
                float w = 0.f;
                for (int p = i; p < j; p++)
#pragma unroll
                    for (int u = 0; u < 16; u++)
                        w += Uf[(i * 16 + r) * 65 + p * 16 + u] * Uf[(p * 16 + u) * 65 + j * 16 + t];
                Wreg[ri] = w;
            }
#pragma unroll
            for (int ri = 0; ri < 4; ri++) {
                float acc = 0.f;
#pragma unroll
                for (int u = 0; u < 16; u++)
                    acc += __shfl(Wreg[ri], (lane & 48) + u, 64) * Uf[(j * 16 + u) * 65 + (j * 16 + t)];
                Xn[ri] = acc;
            }
        }
        __syncthreads();
        if (act) {
#pragma unroll
            for (int ri = 0; ri < 4; ri++)
                Uf[(wv * 16 + q * 4 + ri) * 65 + j * 16 + t] = Xn[ri];
        }
        __syncthreads();
    }
    // sMt[t][s] = X[s][t] (bf16)
#pragma unroll
    for (int i = 0; i < 16; i++) {
        int idx = tid * 16 + i;
        int t = idx >> 6, s = idx & 63;
        sMt[idx] = f2bf((s <= t) ? Uf[s * 65 + t] : 0.f);
    }
    __syncthreads();

    // P4: VQ = Vt x Qt^T -> sVQ  (sV is [v][t])
    {
        f32x4 acc[2][2] = {};
        g64(sV, sQt, acc, m0, n0, lane);
#pragma unroll
        for (int mi = 0; mi < 2; mi++)
#pragma unroll
            for (int ni = 0; ni < 2; ni++)
#pragma unroll
                for (int rg = 0; rg < 4; rg++) {
                    int m = m0 + mi * 16 + (lane >> 4) * 4 + rg;
                    int n = n0 + ni * 16 + (lane & 15);
                    sVQ[m * 64 + n] = f2bf(acc[mi][ni][rg]);
                }
    }
    __syncthreads();

    // P5: VQM = VQ x X ; G1T[t][k] = sum_s X[s][t] Ahat[s][k]
    {
        f32x4 a1[2][2] = {}, a2[2][2] = {};
        g64(sVQ, sMt, a1, m0, n0, lane);
        g64(sMt, sAT, a2, m0, n0, lane);
#pragma unroll
        for (int mi = 0; mi < 2; mi++)
#pragma unroll
            for (int ni = 0; ni < 2; ni++)
#pragma unroll
                for (int rg = 0; rg < 4; rg++) {
                    int m = m0 + mi * 16 + (lane >> 4) * 4 + rg;
                    int n = n0 + ni * 16 + (lane & 15);
                    VQM[ub + m * 64 + n] = f2bf(a1[mi][ni][rg]);
                    G1T[ub + m * 64 + n] = f2bf(a2[mi][ni][rg]);
                }
    }
}

// ---- B: FUSED scan + Y-GEMM. Row-split over v (block = (bh, half), 128 blocks).
//      Waves 0,1: state recurrence (SA in phase 1; S' in phase 2).
//      Waves 2,3: Y for this chunk's t-rows x our v-half, using the previously-idle
//      MFMA slots: phase 1 y += Rhat x Sin^T (sS = state at chunk entry, stable);
//      phase 2 y += PB x SA^T + PK x Vt^T (sSA stable after B2). y -> global f32.
//      SA/Sin never touch HBM. All __syncthreads uniform across 256 threads.
__global__ __launch_bounds__(256, 1) void k_scanfull(
    const u16* __restrict__ G1T, const u16* __restrict__ VQM, const u16* __restrict__ BhatT,
    const u16* __restrict__ KhatT, const u16* __restrict__ Vt, const u16* __restrict__ Rhat,
    const u16* __restrict__ PB, const u16* __restrict__ PK, const float* __restrict__ cumLg,
    float* __restrict__ yb) {
    __shared__ u16 bG1[2][4096], bBh[2][4096], bKh[2][4096];
    __shared__ u16 bRh[2][4096], bPBs[2][4096], bPKs[2][4096];
    __shared__ u16 bVQ[2][2048], bVt[2][2048];
    __shared__ u16 sSA[2048], sS[2048];
    __shared__ float sSf[2048];
    __shared__ float sCumL[2][64];

    int tid = threadIdx.x, wv = tid >> 6, lane = tid & 63;
    int bh = blockIdx.x >> 1;
    int half = blockIdx.x & 1;
    int hoff = half * 2048;            // element offset of our 32-row half in [64][64] bufs
    int n0 = (wv & 1) * 32;            // waves 0,1: n-halves of the state tile
    int m0y = (wv & 1) * 32;           // waves 2,3: t-halves of the Y tile

    for (int i = tid; i < 2048; i += 256) { sSf[i] = 0.f; sS[i] = 0; }

    auto stage = [&](int c, int buf) {
        size_t ub = ((size_t)bh * NC + c) * 4096;
        stage8k(G1T + ub, bG1[buf], tid);
        stage8k(BhatT + ub, bBh[buf], tid);
        stage8k(KhatT + ub, bKh[buf], tid);
        stage8k(Rhat + ub, bRh[buf], tid);
        stage8k(PB + ub, bPBs[buf], tid);
        stage8k(PK + ub, bPKs[buf], tid);
        gload16(VQM + ub + hoff + tid * 8, bVQ[buf] + tid * 8);   // 2048 u16 = 256x16B
        gload16(Vt + ub + hoff + tid * 8, bVt[buf] + tid * 8);
        if (tid < 16) gload16(cumLg + ((size_t)bh * NC + c) * 64 + tid * 4, &sCumL[buf][tid * 4]);
    };

    stage(0, 0);
    for (int c = 0; c < NC; c++) {
        int cur = c & 1;
        __syncthreads();                  // B1: staged data + prev S' visible
        if (c + 1 < NC) stage(c + 1, 1 - cur);
        size_t uy = ((size_t)bh * NC + c) * 4096;

        f32x4 yacc[2][2];
        // ---- phase 1 ----
        if (wv < 2) {
            // gSA: SA = S x G1T-form + VQM   (rows v local 0..32)
            f32x4 acc[2][2];
#pragma unroll
            for (int mi = 0; mi < 2; mi++)
#pragma unroll
                for (int ni = 0; ni < 2; ni++)
#pragma unroll
                    for (int rg = 0; rg < 4; rg++) {
                        int m = mi * 16 + (lane >> 4) * 4 + rg;
                        int n = n0 + ni * 16 + (lane & 15);
                        acc[mi][ni][rg] = bf2f(bVQ[cur][m * 64 + n]);
                    }
            g64(sS, bG1[cur], acc, 0, n0, lane);
#pragma unroll
            for (int mi = 0; mi < 2; mi++)
#pragma unroll
                for (int ni = 0; ni < 2; ni++)
#pragma unroll
                    for (int rg = 0; rg < 4; rg++) {
                        int m = mi * 16 + (lane >> 4) * 4 + rg;
                        int n = n0 + ni * 16 + (lane & 15);
                        sSA[m * 64 + n] = f2bf(acc[mi][ni][rg]);
                    }
        } else {
            // y1 = Rhat x Sin^T (Sin = sS, stable until phase 2)
#pragma unroll
            for (int i = 0; i < 2; i++)
#pragma unroll
                for (int j = 0; j < 2; j++) yacc[i][j] = (f32x4){0.f, 0.f, 0.f, 0.f};
            g64(bRh[cur], sS, yacc, m0y, 0, lane);
        }
        __syncthreads();                  // B2 (also drains prefetch)

        // ---- phase 2 ----
        if (wv < 2) {
            // gS': S' = (S + SA.bhat + Vt.khat) * cumL[k]
            f32x4 acc[2][2] = {};
            g64(sSA, bBh[cur], acc, 0, n0, lane);
            g64(bVt[cur], bKh[cur], acc, 0, n0, lane);
#pragma unroll
            for (int mi = 0; mi < 2; mi++)
#pragma unroll
                for (int ni = 0; ni < 2; ni++)
#pragma unroll
                    for (int rg = 0; rg < 4; rg++) {
                        int m = mi * 16 + (lane >> 4) * 4 + rg;
                        int n = n0 + ni * 16 + (lane & 15);
                        float sn = (acc[mi][ni][rg] + sSf[m * 64 + n]) * sCumL[cur][n];
                        sSf[m * 64 + n] = sn;
                        sS[m * 64 + n] = f2bf(sn);
                    }
        } else {
            // y2 + y3 = PB x SA^T + PK x Vt^T (sSA stable after B2; bVt read-only)
            g64(bPBs[cur], sSA, yacc, m0y, 0, lane);
            g64(bPKs[cur], bVt[cur], yacc, m0y, 0, lane);
#pragma unroll
            for (int mi = 0; mi < 2; mi++)
#pragma unroll
                for (int ni = 0; ni < 2; ni++)
#pragma unroll
                    for (int rg = 0; rg < 4; rg++) {
                        int t = m0y + mi * 16 + (lane >> 4) * 4 + rg;
                        int vl = ni * 16 + (lane & 15);
                        yb[uy + (size_t)t * 64 + half * 32 + vl] = yacc[mi][ni][rg];
                    }
        }
    }
}

// ---- C-lite: GroupNorm + bonus + gate over precomputed y (no MFMA, no LDS) ----
__global__ void k_gnout(const float* __restrict__ yb,
                        const u16* __restrict__ rb, const u16* __restrict__ kb,
                        const u16* __restrict__ vb, const u16* __restrict__ gb,
                        const float* __restrict__ gn_w, const float* __restrict__ gn_b,
                        const float* __restrict__ r_k, u16* __restrict__ yg) {
    int tid = threadIdx.x, wv = tid >> 6, lane = tid & 63;
    int unit = blockIdx.x;
    int c = unit & 15, bh = unit >> 4, h = bh & 31, b = bh >> 5;
    size_t ub = (size_t)unit * 4096;
    int cg = h * 64 + lane;
    float gwn = gn_w[cg], gbn = gn_b[cg], rkc = r_k[cg];
#pragma unroll 2
    for (int i = 0; i < 16; i++) {
        int t = wv * 16 + i;
        float yv = yb[ub + (size_t)t * 64 + lane];
        size_t gi = (((size_t)b * 1024 + c * 64 + t) * 32 + h) * 64 + lane;
        float rv = bf2f(rb[gi]), kv = bf2f(kb[gi]);
        float m1 = yv, m2 = yv * yv, s = rv * kv * rkc;
#pragma unroll
        for (int m = 32; m >= 1; m >>= 1) {
            m1 += __shfl_xor(m1, m, 64);
            m2 += __shfl_xor(m2, m, 64);
            s  += __shfl_xor(s, m, 64);
        }
        m1 *= (1.f / 64.f);
        m2 *= (1.f / 64.f);
        float var = m2 - m1 * m1;
        float xn = (yv - m1) * rsqrtf(var + GN_EPS_C) * gwn + gbn;
        float out = (xn + s * bf2f(vb[gi])) * bf2f(gb[gi]);
        yg[gi] = f2bf(out);
    }
}

// ---------------- launcher ----------------
extern "C" void kernel_launch(void* const* d_in, const int* in_sizes, int n_in,
                              void* d_out, int out_size, void* d_ws, size_t ws_size,
                              hipStream_t stream) {
    const float* x      = (const float*)d_in[0];
    const float* vfirst = (const float*)d_in[1];
    const float* x_r = (const float*)d_in[2];
    const float* x_w = (const float*)d_in[3];
    const float* x_k = (const float*)d_in[4];
    const float* x_v = (const float*)d_in[5];
    const float* x_a = (const float*)d_in[6];
    const float* x_g = (const float*)d_in[7];
    const float* w0 = (const float*)d_in[8];
    const float* w1 = (const float*)d_in[9];
    const float* w2 = (const float*)d_in[10];
    const float* a0 = (const float*)d_in[11];
    const float* a1 = (const float*)d_in[12];
    const float* a2 = (const float*)d_in[13];
    const float* v0 = (const float*)d_in[14];
    const float* v1 = (const float*)d_in[15];
    const float* v2 = (const float*)d_in[16];
    const float* g1 = (const float*)d_in[17];
    const float* g2 = (const float*)d_in[18];
    const float* k_k = (const float*)d_in[19];
    const float* k_a = (const float*)d_in[20];
    const float* r_k = (const float*)d_in[21];
    const float* W_r = (const float*)d_in[22];
    const float* W_k = (const float*)d_in[23];
    const float* W_v = (const float*)d_in[24];
    const float* W_o = (const float*)d_in[25];
    const float* gn_w = (const float*)d_in[26];
    const float* gn_b = (const float*)d_in[27];
    (void)in_sizes; (void)n_in; (void)out_size; (void)ws_size;

    char* wsp = (char*)d_ws;
    size_t off = 0;
    auto alloc = [&](size_t bytes) -> char* {
        char* p = wsp + off;
        off += (bytes + 255) & ~(size_t)255;
        return p;
    };
    const size_t MAT = (size_t)BT * C_;  // 4M elements

    u16* WrT = (u16*)alloc(MAT * 2);
    u16* WkT = (u16*)alloc(MAT * 2);
    u16* WvT = (u16*)alloc(MAT * 2);
    u16* WoT = (u16*)alloc(MAT * 2);
    u16* w1T = (u16*)alloc((size_t)128 * 2048 * 2);
    u16* a1T = (u16*)alloc((size_t)128 * 2048 * 2);
    u16* v1T = (u16*)alloc((size_t)128 * 2048 * 2);
    u16* g1T = (u16*)alloc((size_t)256 * 2048 * 2);
    u16* w2T = (u16*)alloc((size_t)2048 * 96 * 2);
    u16* a2T = (u16*)alloc((size_t)2048 * 96 * 2);
    u16* v2T = (u16*)alloc((size_t)2048 * 64 * 2);
    u16* g2T = (u16*)alloc((size_t)2048 * 256 * 2);
    char* xmixR = alloc(6 * MAT * 2);          // 48MB; reused by scan scratch
    u16* xmix = (u16*)xmixR;
    u16* hbuf = (u16*)alloc((size_t)BT * 512 * 2);
    u16* rbuf = (u16*)alloc(MAT * 2);
    u16* kbuf = (u16*)alloc(MAT * 2);
    u16* vbuf = (u16*)alloc(MAT * 2);
    u16* asig = (u16*)alloc(MAT * 2);
    float* lwdec = (float*)alloc(MAT * 4);
    u16* gbuf = (u16*)alloc(MAT * 2);
    u16* ygbuf = (u16*)alloc(MAT * 2);
    const size_t UE = (size_t)UNITS * 4096;
    u16* Ahat  = (u16*)alloc(UE * 2);   // backing store for hp/opart aliases only
    u16* Khat  = (u16*)alloc(UE * 2);
    u16* Rhat  = (u16*)alloc(UE * 2);
    u16* Vt    = (u16*)alloc(UE * 2);
    u16* BhatT = (u16*)alloc(UE * 2);
    u16* KhatT = (u16*)alloc(UE * 2);
    float* cumLg = (float*)alloc((size_t)UNITS * 64 * 4);
    (void)Khat;
    // aliases over xmix scratch (dead after rkvup):
    u16* PB   = (u16*)(xmixR + (size_t)0 * 1024 * 1024);
    u16* PK   = (u16*)(xmixR + (size_t)8 * 1024 * 1024);
    u16* G1T  = (u16*)(xmixR + (size_t)16 * 1024 * 1024);
    u16* VQM  = (u16*)(xmixR + (size_t)24 * 1024 * 1024);
    float* ybuf = (float*)(xmixR + (size_t)32 * 1024 * 1024);   // 16MB f32 (ex SA/Sin slots)
    // split-K partials for upproj: 4 x 2048x512 f32 = 16MB over Ahat+Khat (dead regions)
    float* hp = (float*)Ahat;
    // o-proj split-K=2 partials: 2 x 2048x2048 f32 = 32MB over Ahat..Vt (dead after scan)
    float* opart = (float*)Ahat;

    // 1+2) MERGED preprocessing: 4 big transposes + 8 LoRA transposes + token-shift mix
    PreArgs pa;
    pa.big[0] = {W_r, WrT, 2048, 2048};
    pa.big[1] = {W_k, WkT, 2048, 2048};
    pa.big[2] = {W_v, WvT, 2048, 2048};
    pa.big[3] = {W_o, WoT, 2048, 2048};
    pa.sm[0] = {w1, w1T, 2048, 96};
    pa.sm[1] = {a1, a1T, 2048, 96};
    pa.sm[2] = {v1, v1T, 2048, 64};
    pa.sm[3] = {g1, g1T, 2048, 256};
    pa.sm[4] = {w2, w2T, 96, 2048};
    pa.sm[5] = {a2, a2T, 96, 2048};
    pa.sm[6] = {v2, v2T, 64, 2048};
    pa.sm[7] = {g2, g2T, 256, 2048};
    pa.x = x;
    pa.cs[0] = x_r; pa.cs[1] = x_w; pa.cs[2] = x_k;
    pa.cs[3] = x_v; pa.cs[4] = x_a; pa.cs[5] = x_g;
    pa.xmix = xmix;
    k_pre<<<dim3(64, 64, 6), 256, 0, stream>>>(pa);

    // 3+4) MERGED: r/k/v projections + LoRA up-projections (split-K=4 partials; BK=128 core)
    k_rkvup<<<dim3(16, 16, 7), 256, 0, stream>>>(xmix, WrT, WkT, WvT, w1T, a1T, v1T, g1T,
                                                 rbuf, kbuf, vbuf, hp);
    k_upred<<<dim3(1024), 256, 0, stream>>>(hp, hbuf);

    // 5) LoRA down-projections (BK=64 core)
    k_down4<<<dim3(16, 16, 4), 256, 0, stream>>>(hbuf, w2T, a2T, v2T, g2T,
                                                 lwdec, asig, vbuf, gbuf, w0, a0, v0, vfirst);

    // 6) FUSED scan phase A: prep (block-scan cumsum) + chunkops
    k_prepchunk<<<dim3(UNITS), 256, 0, stream>>>(lwdec, asig, kbuf, rbuf, vbuf, k_k, k_a,
                                                 Rhat, Vt, BhatT, KhatT, cumLg,
                                                 PB, PK, G1T, VQM);

    // 7) FUSED sequential scan + Y GEMM (waves 2,3 compute y; SA/Sin stay on-chip)
    k_scanfull<<<dim3(B_ * H_ * 2), 256, 0, stream>>>(G1T, VQM, BhatT, KhatT, Vt,
                                                      Rhat, PB, PK, cumLg, ybuf);

    // 8) GroupNorm + bonus + gate (elementwise, reads y f32)
    k_gnout<<<dim3(UNITS), 256, 0, stream>>>(ybuf, rbuf, kbuf, vbuf, gbuf,
                                             gn_w, gn_b, r_k, ygbuf);

    // 9) output projection: split-K=2 (512 blocks, K=1024, BK=128 core) + reduce
    k_oproj<<<dim3(16, 16, 2), 256, 0, stream>>>(ygbuf, WoT, opart);
    k_ored<<<dim3(4096), 256, 0, stream>>>(opart, (float*)d_out);
}